// Round 7
// baseline (1039.626 us; speedup 1.0000x reference)
//
#include <hip/hip_runtime.h>

typedef unsigned short u16;
typedef __bf16 bf16x8 __attribute__((ext_vector_type(8)));
typedef float f32x4 __attribute__((ext_vector_type(4)));

#define D_MODEL 256
#define D_INNER 1024
#define NST     16
#define SEQ     2048
#define LOG2E   1.4426950408889634f

struct TrueT  { static constexpr bool value = true;  };
struct FalseT { static constexpr bool value = false; };

static __device__ __forceinline__ float bf2f(u16 u) {
    union { float f; unsigned v; } x; x.v = ((unsigned)u) << 16; return x.f;
}
static __device__ __forceinline__ u16 f2bf(float f) {
    union { float f; unsigned u; } x; x.f = f;
    unsigned r = 0x7FFF + ((x.u >> 16) & 1);
    return (u16)((x.u + r) >> 16);
}

// async global->LDS, 16B per lane, LDS dest = wave-uniform base + lane*16
#define GLOAD_LDS16(g, l)                                            \
    __builtin_amdgcn_global_load_lds(                                \
        (const __attribute__((address_space(1))) void*)(g),          \
        (__attribute__((address_space(3))) void*)(l), 16, 0, 0)

// dA[n] = e1^(n+1), n=0..15, via binary decomposition (16 muls, depth ~5)
static __device__ __forceinline__ void dA_pow(float e1, float* dA) {
    float e2 = e1 * e1, e3 = e2 * e1, e4 = e2 * e2;
    float e8 = e4 * e4, e12 = e8 * e4;
    dA[0] = e1;       dA[1] = e2;       dA[2] = e3;       dA[3] = e4;
    dA[4] = e4 * e1;  dA[5] = e4 * e2;  dA[6] = e4 * e3;  dA[7] = e8;
    dA[8] = e8 * e1;  dA[9] = e8 * e2;  dA[10] = e8 * e3; dA[11] = e12;
    dA[12] = e12 * e1; dA[13] = e12 * e2; dA[14] = e12 * e3; dA[15] = e8 * e8;
}

// ---- RMSNorm -> split-bf16 pair output: row = [256 hi | 256 lo] u16 ----
__global__ __launch_bounds__(256) void rmsnorm_k(const float* __restrict__ x,
                                                 const float* __restrict__ w,
                                                 u16* __restrict__ xnp) {
    int row = blockIdx.x, t = threadIdx.x;
    float v = x[(size_t)row * D_MODEL + t];
    float s = v * v;
    #pragma unroll
    for (int o = 32; o; o >>= 1) s += __shfl_xor(s, o, 64);
    __shared__ float red[4];
    if ((t & 63) == 0) red[t >> 6] = s;
    __syncthreads();
    float tot = red[0] + red[1] + red[2] + red[3];
    float scale = rsqrtf(tot * (1.0f / D_MODEL) + 1e-5f);
    float xv = v * scale * w[t];
    u16 hi = f2bf(xv);
    u16 lo = f2bf(xv - bf2f(hi));
    xnp[(size_t)row * 512 + t] = hi;
    xnp[(size_t)row * 512 + 256 + t] = lo;
}

// ---- weight split: src[N*K] f32 -> dst[N][2K] bf16 (hi | lo) -----------
__global__ __launch_bounds__(256) void wsplit_k(const float* __restrict__ src,
                                                u16* __restrict__ dst, int K) {
    int i = blockIdx.x * 256 + threadIdx.x;
    int n = i / K, k = i - n * K;
    float v = src[i];
    u16 hi = f2bf(v);
    u16 lo = f2bf(v - bf2f(hi));
    dst[(size_t)n * 2 * K + k] = hi;
    dst[(size_t)n * 2 * K + K + k] = lo;
}

// ---- weight split with zero-padded rows (for x_proj: 48 real -> 128) ----
__global__ __launch_bounds__(256) void wsplit_pad_k(const float* __restrict__ src,
                                                    u16* __restrict__ dst, int K,
                                                    int Nreal) {
    int i = blockIdx.x * 256 + threadIdx.x;
    int n = i / K, k = i - n * K;
    float v = 0.0f;
    if (n < Nreal) v = src[i];
    u16 hi = f2bf(v);
    u16 lo = f2bf(v - bf2f(hi));
    dst[(size_t)n * 2 * K + k] = hi;
    dst[(size_t)n * 2 * K + K + k] = lo;
}

// ---- FUSED split-bf16 MFMA GEMM, 128x128 tile ---------------------------
// Per 32-real-k window, stage {Ah,Al,Wh,Wl} once and compute all 3 split
// terms (AhWh + AhWl + AlWh) into the same acc: 16 b128 reads per 48 MFMA.
// LDS row = 128B: [hi 32 u16 | lo 32 u16]; lo sourced from col KL+k of the
// pair buffers (per-lane source of global_load_lds; LDS dest linear).
// 16B-chunk XOR swizzle (chunk ^= row&7) on source, undone on read (R1: 0
// conflicts).  kslice = REAL k per z-slice (multiple of 32).
__global__ __launch_bounds__(256) void gemm_mfma(const u16* __restrict__ Ap, int lda,
                                                 const u16* __restrict__ Wp, int ldw,
                                                 float* __restrict__ C, int ldc,
                                                 int KL, int kslice, size_t zstride,
                                                 int Nreal) {
    __shared__ u16 As[128][64];
    __shared__ u16 Ws[128][64];
    const int m0 = blockIdx.x * 128, n0 = blockIdx.y * 128;
    const int tid = threadIdx.x;
    const int wave = tid >> 6, lane = tid & 63;
    const int wm = (wave >> 1) * 64, wn = (wave & 1) * 64;
    const int lm = lane & 15, quad = lane >> 4;

    const int srow = lane >> 3;                 // == row & 7
    const int schunk = (lane & 7) ^ srow;       // swizzled logical chunk
    const int scol = (schunk < 4) ? schunk * 8 : KL + (schunk - 4) * 8;
    const int rloc = wave * 8 + srow;

    f32x4 acc[4][4] = {};

    const int kb0 = blockIdx.z * kslice;
    for (int ko = kb0; ko < kb0 + kslice; ko += 32) {
        #pragma unroll
        for (int p = 0; p < 4; p++) {
            int row = p * 32 + rloc;
            GLOAD_LDS16(Ap + (size_t)(m0 + row) * lda + ko + scol,
                        &As[p * 32 + wave * 8][0]);
            GLOAD_LDS16(Wp + (size_t)(n0 + row) * ldw + ko + scol,
                        &Ws[p * 32 + wave * 8][0]);
        }
        __syncthreads();
        const int ph = ((quad ^ lm) & 7) * 8;   // phys offset of logical 'quad'
        bf16x8 bh[4], bl[4];
        #pragma unroll
        for (int j = 0; j < 4; j++) {
            const u16* wr = &Ws[wn + j * 16 + lm][0];
            bh[j] = *(const bf16x8*)(wr + ph);
            bl[j] = *(const bf16x8*)(wr + (ph ^ 32));
        }
        #pragma unroll
        for (int i = 0; i < 4; i++) {
            const u16* ar = &As[wm + i * 16 + lm][0];
            bf16x8 ah = *(const bf16x8*)(ar + ph);
            bf16x8 al = *(const bf16x8*)(ar + (ph ^ 32));
            #pragma unroll
            for (int j = 0; j < 4; j++) {
                acc[i][j] = __builtin_amdgcn_mfma_f32_16x16x32_bf16(
                    ah, bh[j], acc[i][j], 0, 0, 0);
                acc[i][j] = __builtin_amdgcn_mfma_f32_16x16x32_bf16(
                    ah, bl[j], acc[i][j], 0, 0, 0);
                acc[i][j] = __builtin_amdgcn_mfma_f32_16x16x32_bf16(
                    al, bh[j], acc[i][j], 0, 0, 0);
            }
        }
        __syncthreads();
    }

    float* Cz = C + zstride * blockIdx.z;
    #pragma unroll
    for (int i = 0; i < 4; i++)
        #pragma unroll
        for (int j = 0; j < 4; j++)
            #pragma unroll
            for (int r = 0; r < 4; r++) {
                int mrow = m0 + wm + i * 16 + quad * 4 + r;   // C/D: row=quad*4+reg
                int ncol = n0 + wn + j * 16 + lm;             //      col=lane&15
                if (ncol < Nreal)
                    Cz[(size_t)mrow * ldc + ncol] = acc[i][j][r];
            }
}

// ------ reduce 8 x_proj partials -> dbl[R*48] -----------------------------
__global__ __launch_bounds__(256) void reduce_dbl_k(const float* __restrict__ pbuf,
                                                    float* __restrict__ dbl,
                                                    size_t RS) {
    size_t e = (size_t)blockIdx.x * 256 + threadIdx.x;
    float v = 0.0f;
    #pragma unroll
    for (int z = 0; z < 8; z++) v += pbuf[z * RS + e];
    dbl[e] = v;
}

// ------ reduce 4 out_proj partials + residual -> out[m, coff + n] ---------
__global__ __launch_bounds__(256) void reduce_out_k(const float* __restrict__ pbuf,
                                                    const float* __restrict__ res,
                                                    float* __restrict__ out,
                                                    int M, int coff) {
    int idx = blockIdx.x * 256 + threadIdx.x;
    int m = idx >> 6, n4 = (idx & 63) * 4;
    size_t e = (size_t)m * 256 + n4;
    size_t stride = (size_t)M * 256;
    float4 v = *(const float4*)(res + e);
    #pragma unroll
    for (int s = 0; s < 4; s++) {
        float4 p = *(const float4*)(pbuf + s * stride + e);
        v.x += p.x; v.y += p.y; v.z += p.z; v.w += p.w;
    }
    *(float4*)(out + (size_t)m * 512 + coff + n4) = v;
}

// ---- depthwise causal conv + SiLU; out = split-bf16 pair ----------------
__global__ __launch_bounds__(256) void conv_silu_k(const float* __restrict__ xz,
                                                   const float* __restrict__ cw,
                                                   const float* __restrict__ cb,
                                                   u16* __restrict__ xcp, int dir) {
    int bx = blockIdx.x;
    int dgrp = bx & 3;
    int rowgrp = bx >> 2;
    int l0 = (rowgrp & (SEQ / 4 - 1)) * 4;
    int b = rowgrp >> 9;
    int d = dgrp * 256 + threadIdx.x;

    int base = dir ? l0 : (l0 - 3);
    float x[7];
    #pragma unroll
    for (int i = 0; i < 7; i++) {
        int lr = base + i;
        x[i] = (lr >= 0 && lr < SEQ)
             ? xz[((size_t)b * SEQ + lr) * (2 * D_INNER) + d] : 0.0f;
    }
    float w0 = cw[d * 4 + 0], w1 = cw[d * 4 + 1];
    float w2 = cw[d * 4 + 2], w3 = cw[d * 4 + 3];
    float bias = cb[d];

    #pragma unroll
    for (int li = 0; li < 4; li++) {
        float acc;
        if (dir == 0)
            acc = bias + w0 * x[li] + w1 * x[li + 1] + w2 * x[li + 2] + w3 * x[li + 3];
        else
            acc = bias + w3 * x[li] + w2 * x[li + 1] + w1 * x[li + 2] + w0 * x[li + 3];
        float s = acc / (1.0f + __expf(-acc));
        u16 hi = f2bf(s);
        u16 lo = f2bf(s - bf2f(hi));
        size_t row = (size_t)b * SEQ + l0 + li;
        xcp[row * 2048 + d] = hi;
        xcp[row * 2048 + D_INNER + d] = lo;
    }
}

// ---- scan phase 1: per-chunk H (h_in=0) and P; dbl staged in LDS --------
// launch_bounds(256,8): keep VGPR <= 64-waves/EU budget so 8 waves/EU fit
// (R6 lesson: at VGPR=64 residency capped ~16/CU and extra wave supply ran
// as sequential batches -> no speedup).
__global__ __launch_bounds__(256, 8) void scan_p1(const u16* __restrict__ xcp,
                                               const float* __restrict__ dbl,
                                               const float* __restrict__ dtw,
                                               const float* __restrict__ dtb,
                                               const float* __restrict__ Alog,
                                               float* __restrict__ P,
                                               float* __restrict__ H,
                                               int nb, int TC, int dir) {
    __shared__ float sdbl[32 * 48];            // TC <= 32
    int t = threadIdx.x;
    int nblk4 = nb * 4;
    int c = blockIdx.x / nblk4;
    int rem = blockIdx.x - c * nblk4;
    int b = rem >> 2, dblk = rem & 3;
    int d = dblk * 256 + t;

    int lbase = dir ? (SEQ - (c + 1) * TC) : (c * TC);
    {
        const float* src = dbl + ((size_t)b * SEQ + lbase) * 48;
        int nf4 = TC * 12;
        for (int i = t; i < nf4; i += 256)
            *(float4*)&sdbl[i * 4] = *(const float4*)(src + i * 4);
    }

    float A2[16], wdt[16];
    const float* ap = Alog + (size_t)d * NST;
    const float* wp = dtw + (size_t)d * NST;
    #pragma unroll
    for (int n = 0; n < 16; n++) { A2[n] = -__expf(ap[n]) * LOG2E; wdt[n] = wp[n]; }
    float bdt = dtb[d];
    bool fast = true;
    #pragma unroll
    for (int n = 0; n < 16; n++)
        fast = fast && (fabsf(A2[n] - (n + 1) * A2[0]) < 1e-3f);

    float h[16] = {0,0,0,0,0,0,0,0,0,0,0,0,0,0,0,0};
    float S = 0.0f;

    int lstep = dir ? -1 : 1;
    int l0 = dir ? (lbase + TC - 1) : lbase;
    const u16* up = xcp + ((size_t)b * SEQ + l0) * 2048 + d;
    ptrdiff_t ups = (ptrdiff_t)lstep * 2048;
    const float* dr = sdbl + (dir ? (TC - 1) * 48 : 0);
    ptrdiff_t drs = (ptrdiff_t)lstep * 48;

    __syncthreads();

    auto body = [&](auto FC) {
        constexpr bool F = decltype(FC)::value;
        u16 uh = up[0], ul = up[D_INNER];          // current-step u
        #pragma unroll 2
        for (int s = 0; s < TC; s++) {
            u16 nh = up[ups], nl = up[ups + D_INNER];   // prefetch next step
            float dl[16], B[16];
            #pragma unroll
            for (int n = 0; n < 16; n += 4) {
                *(float4*)&dl[n] = *(const float4*)(dr + n);
                *(float4*)&B[n]  = *(const float4*)(dr + 16 + n);
            }
            float u = bf2f(uh) + bf2f(ul);
            float acc = bdt;
            #pragma unroll
            for (int n = 0; n < 16; n++) acc += dl[n] * wdt[n];
            float dt = (acc > 20.0f) ? acc : __logf(1.0f + __expf(acc));
            float dtu = dt * u;
            S += dt;
            float dA[16];
            if (F) {
                dA_pow(exp2f(A2[0] * dt), dA);
            } else {
                #pragma unroll
                for (int n = 0; n < 16; n++) dA[n] = exp2f(A2[n] * dt);
            }
            #pragma unroll
            for (int n = 0; n < 16; n++)
                h[n] = h[n] * dA[n] + dtu * B[n];
            uh = nh; ul = nl;
            dr += drs; up += ups;
        }
    };
    if (fast) body(TrueT{}); else body(FalseT{});

    size_t NCH = (size_t)nb * 16384;
    size_t base = (size_t)c * NCH + ((size_t)b * 1024 + d) * 16;
    float Pv[16];
    if (fast) {
        dA_pow(exp2f(A2[0] * S), Pv);
    } else {
        #pragma unroll
        for (int n = 0; n < 16; n++) Pv[n] = exp2f(A2[n] * S);
    }
    #pragma unroll
    for (int n = 0; n < 16; n += 4) {
        *(float4*)&H[base + n] = *(float4*)&h[n];
        *(float4*)&P[base + n] = *(float4*)&Pv[n];
    }
}

// ------- scan phase 2: combine chunk states; H repurposed as h_in --------
__global__ __launch_bounds__(256) void scan_p2(const float* __restrict__ P,
                                               float* __restrict__ H,
                                               int NCH, int NC) {
    size_t chain = (size_t)blockIdx.x * 256 + threadIdx.x;
    float h = 0.0f;
    for (int c = 0; c < NC; c++) {
        size_t i = (size_t)c * NCH + chain;
        float Hc = H[i], Pc = P[i];
        H[i] = h;
        h = Hc + Pc * h;
    }
}

// ---- scan phase 3: recurrence + silu(z) + y pair; dbl staged in LDS -----
__global__ __launch_bounds__(256, 8) void scan_p3(const u16* __restrict__ xcp,
                                               const float* __restrict__ dbl,
                                               const float* __restrict__ dtw,
                                               const float* __restrict__ dtb,
                                               float* __restrict__ xz,
                                               const float* __restrict__ Alog,
                                               const float* __restrict__ Dp,
                                               const float* __restrict__ hin,
                                               int nb, int TC, int dir) {
    __shared__ float sdbl[32 * 48];
    int t = threadIdx.x;
    int nblk4 = nb * 4;
    int c = blockIdx.x / nblk4;
    int rem = blockIdx.x - c * nblk4;
    int b = rem >> 2, dblk = rem & 3;
    int d = dblk * 256 + t;

    int lbase = dir ? (SEQ - (c + 1) * TC) : (c * TC);
    {
        const float* src = dbl + ((size_t)b * SEQ + lbase) * 48;
        int nf4 = TC * 12;
        for (int i = t; i < nf4; i += 256)
            *(float4*)&sdbl[i * 4] = *(const float4*)(src + i * 4);
    }

    float A2[16], wdt[16];
    const float* ap = Alog + (size_t)d * NST;
    const float* wp = dtw + (size_t)d * NST;
    #pragma unroll
    for (int n = 0; n < 16; n++) { A2[n] = -__expf(ap[n]) * LOG2E; wdt[n] = wp[n]; }
    float bdt = dtb[d];
    float Dd = Dp[d];
    bool fast = true;
    #pragma unroll
    for (int n = 0; n < 16; n++)
        fast = fast && (fabsf(A2[n] - (n + 1) * A2[0]) < 1e-3f);

    size_t NCH = (size_t)nb * 16384;
    size_t base = (size_t)c * NCH + ((size_t)b * 1024 + d) * 16;
    float h[16];
    #pragma unroll
    for (int n = 0; n < 16; n += 4)
        *(float4*)&h[n] = *(const float4*)&hin[base + n];

    int lstep = dir ? -1 : 1;
    int l0 = dir ? (lbase + TC - 1) : lbase;
    size_t row0 = (size_t)b * SEQ + l0;
    const u16* up = xcp + row0 * 2048 + d;
    const float* zp = xz + row0 * 2048 + D_INNER + d;
    u16* yp = (u16*)(xz + row0 * 2048) + d;
    ptrdiff_t ups = (ptrdiff_t)lstep * 2048;
    ptrdiff_t zps = (ptrdiff_t)lstep * 2048;
    ptrdiff_t yps = (ptrdiff_t)lstep * 4096;   // u16 pitch of a 2048-float row
    const float* dr = sdbl + (dir ? (TC - 1) * 48 : 0);
    ptrdiff_t drs = (ptrdiff_t)lstep * 48;

    __syncthreads();

    auto body = [&](auto FC) {
        constexpr bool F = decltype(FC)::value;
        u16 uh = up[0], ul = up[D_INNER];
        float zc = *zp;
        #pragma unroll 2
        for (int s = 0; s < TC; s++) {
            u16 nh = up[ups], nl = up[ups + D_INNER];   // prefetch next step
            float zn = zp[zps];
            float dl[16], B[16], Cv[16];
            #pragma unroll
            for (int n = 0; n < 16; n += 4) {
                *(float4*)&dl[n] = *(const float4*)(dr + n);
                *(float4*)&B[n]  = *(const float4*)(dr + 16 + n);
                *(float4*)&Cv[n] = *(const float4*)(dr + 32 + n);
            }
            float u = bf2f(uh) + bf2f(ul);
            float acc = bdt;
            #pragma unroll
            for (int n = 0; n < 16; n++) acc += dl[n] * wdt[n];
            float dt = (acc > 20.0f) ? acc : __logf(1.0f + __expf(acc));
            float dtu = dt * u;
            float dA[16];
            if (F) {
                dA_pow(exp2f(A2[0] * dt), dA);
            } else {
                #pragma unroll
                for (int n = 0; n < 16; n++) dA[n] = exp2f(A2[n] * dt);
            }
            #pragma unroll
            for (int n = 0; n < 16; n++)
                h[n] = h[n] * dA[n] + dtu * B[n];

            float p0 = h[0]*Cv[0] + h[1]*Cv[1] + h[2]*Cv[2] + h[3]*Cv[3];
            float p1 = h[4]*Cv[4] + h[5]*Cv[5] + h[6]*Cv[6] + h[7]*Cv[7];
            float p2 = h[8]*Cv[8] + h[9]*Cv[9] + h[10]*Cv[10] + h[11]*Cv[11];
            float p3 = h[12]*Cv[12] + h[13]*Cv[13] + h[14]*Cv[14] + h[15]*Cv[15];

            float g = zc / (1.0f + __expf(-zc));
            float y = ((p0 + p1) + (p2 + p3) + u * Dd) * g;

            u16 hi = f2bf(y);
            yp[0] = hi;
            yp[D_INNER] = f2bf(y - bf2f(hi));

            uh = nh; ul = nl; zc = zn;
            dr += drs; up += ups; zp += zps; yp += yps;
        }
    };
    if (fast) body(TrueT{}); else body(FalseT{});
}

// ---------------- host launch --------------------------------------------
extern "C" void kernel_launch(void* const* d_in, const int* in_sizes, int n_in,
                              void* d_out, int out_size, void* d_ws, size_t ws_size,
                              hipStream_t stream) {
    const float* input = (const float*)d_in[0];
    float* out = (float*)d_out;

    const size_t wspl = (size_t)(2048 * 512 + 256 * 2048 + 128 * 2048) * 2;
    const int TC = 32;                 // R6 lesson: TC=16 doubles P/H+p2 cost
    // nb = batches per pass; try 8 (single pass/dir -> 2x wave supply for
    // scans), fall back if workspace is short.
    // invariant: out_proj split-K partials (4*nb*SEQ*256 floats) == P+H
    // total (2*(SEQ/32)*nb*16384) -> always fits.
    auto fits = [&](int nb_) {
        size_t ph2 = 2ull * (SEQ / TC) * nb_ * 16384 * 4;
        size_t per = (size_t)2048 * (256 + 2048 + 1024 + 48) * 4 * nb_;
        return ph2 + per + wspl <= ws_size;
    };
    int nb = 8;
    while (nb > 1 && !fits(nb)) nb >>= 1;
    const int NC = SEQ / TC;
    const int R = nb * SEQ;
    const int NCH = nb * 16384;
    const size_t PHsz = (size_t)NC * NCH;       // floats per P/H array

    float* P    = (float*)d_ws;        // xproj/out_proj partials / scan P
    float* H    = P + PHsz;
    float* xnf  = H + PHsz;
    float* xz   = xnf + (size_t)R * D_MODEL;
    float* xcyf = xz  + (size_t)R * 2 * D_INNER;
    float* dbl  = xcyf + (size_t)R * D_INNER;
    u16*  winp  = (u16*)(dbl + (size_t)R * 48);
    u16*  woutp = winp + (size_t)2048 * 512;
    u16*  xpp   = woutp + (size_t)256 * 2048;   // padded to 128 rows (zeros)
    u16*  xnp   = (u16*)xnf;
    u16*  xcp   = (u16*)xcyf;

    for (int dir = 0; dir < 2; dir++) {
        int o = 1 + dir * 10;
        const float* nw   = (const float*)d_in[o + 0];
        const float* win  = (const float*)d_in[o + 1];
        const float* cw   = (const float*)d_in[o + 2];
        const float* cb   = (const float*)d_in[o + 3];
        const float* xp   = (const float*)d_in[o + 4];
        const float* dtw  = (const float*)d_in[o + 5];
        const float* dtbv = (const float*)d_in[o + 6];
        const float* Alog = (const float*)d_in[o + 7];
        const float* Dp   = (const float*)d_in[o + 8];
        const float* wout = (const float*)d_in[o + 9];

        wsplit_k<<<2048 * 256 / 256, 256, 0, stream>>>(win, winp, D_MODEL);
        wsplit_k<<<256 * 1024 / 256, 256, 0, stream>>>(wout, woutp, D_INNER);
        wsplit_pad_k<<<128 * 1024 / 256, 256, 0, stream>>>(xp, xpp, D_INNER, 48);

        for (int b0 = 0; b0 < 8; b0 += nb) {
            const float* xin = input + (size_t)b0 * SEQ * D_MODEL;
            float* cout = out + (size_t)b0 * SEQ * 2 * D_MODEL;

            rmsnorm_k<<<R, 256, 0, stream>>>(xin, nw, xnp);
            // in_proj: xz[R,2048] = xn * win^T, KL=256 -> 8 fused windows
            gemm_mfma<<<dim3(R / 128, 16, 1), 256, 0, stream>>>(
                xnp, 512, winp, 512, xz, 2 * D_INNER, D_MODEL, D_MODEL, 0,
                2 * D_INNER);
            conv_silu_k<<<R, 256, 0, stream>>>(xz, cw, cb, xcp, dir);
            // x_proj: partials[8][R,48], KL=1024, split-K=8 -> 4 windows each
            gemm_mfma<<<dim3(R / 128, 1, 8), 256, 0, stream>>>(
                xcp, 2048, xpp, 2048, P, 48, D_INNER, D_INNER / 8,
                (size_t)R * 48, 48);
            reduce_dbl_k<<<R * 48 / 256, 256, 0, stream>>>(P, dbl, (size_t)R * 48);
            scan_p1<<<NC * nb * 4, 256, 0, stream>>>(
                xcp, dbl, dtw, dtbv, Alog, P, H, nb, TC, dir);
            scan_p2<<<NCH / 256, 256, 0, stream>>>(P, H, NCH, NC);
            scan_p3<<<NC * nb * 4, 256, 0, stream>>>(
                xcp, dbl, dtw, dtbv, xz, Alog, Dp, H, nb, TC, dir);
            // out_proj: y_pair * wout^T, KL=1024, split-K=4 -> 8 windows each
            gemm_mfma<<<dim3(R / 128, 2, 4), 256, 0, stream>>>(
                (const u16*)xz, 4096, woutp, 2048, P, 256, D_INNER, D_INNER / 4,
                (size_t)R * 256, 256);
            reduce_out_k<<<R * 64 / 256, 256, 0, stream>>>(
                P, xin, cout, R, dir * D_MODEL);
        }
    }
}

// Round 8
// 865.442 us; speedup vs baseline: 1.2013x; 1.2013x over previous
//
#include <hip/hip_runtime.h>

typedef unsigned short u16;
typedef __bf16 bf16x8 __attribute__((ext_vector_type(8)));
typedef float f32x4 __attribute__((ext_vector_type(4)));

#define D_MODEL 256
#define D_INNER 1024
#define NST     16
#define SEQ     2048
#define LOG2E   1.4426950408889634f

struct TrueT  { static constexpr bool value = true;  };
struct FalseT { static constexpr bool value = false; };

static __device__ __forceinline__ float bf2f(u16 u) {
    union { float f; unsigned v; } x; x.v = ((unsigned)u) << 16; return x.f;
}
static __device__ __forceinline__ u16 f2bf(float f) {
    union { float f; unsigned u; } x; x.f = f;
    unsigned r = 0x7FFF + ((x.u >> 16) & 1);
    return (u16)((x.u + r) >> 16);
}

// async global->LDS, 16B per lane, LDS dest = wave-uniform base + lane*16
#define GLOAD_LDS16(g, l)                                            \
    __builtin_amdgcn_global_load_lds(                                \
        (const __attribute__((address_space(1))) void*)(g),          \
        (__attribute__((address_space(3))) void*)(l), 16, 0, 0)

// dA[n] = e1^(n+1), n=0..15, via binary decomposition (16 muls, depth ~5)
static __device__ __forceinline__ void dA_pow(float e1, float* dA) {
    float e2 = e1 * e1, e3 = e2 * e1, e4 = e2 * e2;
    float e8 = e4 * e4, e12 = e8 * e4;
    dA[0] = e1;       dA[1] = e2;       dA[2] = e3;       dA[3] = e4;
    dA[4] = e4 * e1;  dA[5] = e4 * e2;  dA[6] = e4 * e3;  dA[7] = e8;
    dA[8] = e8 * e1;  dA[9] = e8 * e2;  dA[10] = e8 * e3; dA[11] = e12;
    dA[12] = e12 * e1; dA[13] = e12 * e2; dA[14] = e12 * e3; dA[15] = e8 * e8;
}

// ---- RMSNorm -> split-bf16 pair output: row = [256 hi | 256 lo] u16 ----
__global__ __launch_bounds__(256) void rmsnorm_k(const float* __restrict__ x,
                                                 const float* __restrict__ w,
                                                 u16* __restrict__ xnp) {
    int row = blockIdx.x, t = threadIdx.x;
    float v = x[(size_t)row * D_MODEL + t];
    float s = v * v;
    #pragma unroll
    for (int o = 32; o; o >>= 1) s += __shfl_xor(s, o, 64);
    __shared__ float red[4];
    if ((t & 63) == 0) red[t >> 6] = s;
    __syncthreads();
    float tot = red[0] + red[1] + red[2] + red[3];
    float scale = rsqrtf(tot * (1.0f / D_MODEL) + 1e-5f);
    float xv = v * scale * w[t];
    u16 hi = f2bf(xv);
    u16 lo = f2bf(xv - bf2f(hi));
    xnp[(size_t)row * 512 + t] = hi;
    xnp[(size_t)row * 512 + 256 + t] = lo;
}

// ---- weight split: src[N*K] f32 -> dst[N][2K] bf16 (hi | lo) -----------
__global__ __launch_bounds__(256) void wsplit_k(const float* __restrict__ src,
                                                u16* __restrict__ dst, int K) {
    int i = blockIdx.x * 256 + threadIdx.x;
    int n = i / K, k = i - n * K;
    float v = src[i];
    u16 hi = f2bf(v);
    u16 lo = f2bf(v - bf2f(hi));
    dst[(size_t)n * 2 * K + k] = hi;
    dst[(size_t)n * 2 * K + K + k] = lo;
}

// ---- weight split with zero-padded rows (for x_proj: 48 real -> 128) ----
__global__ __launch_bounds__(256) void wsplit_pad_k(const float* __restrict__ src,
                                                    u16* __restrict__ dst, int K,
                                                    int Nreal) {
    int i = blockIdx.x * 256 + threadIdx.x;
    int n = i / K, k = i - n * K;
    float v = 0.0f;
    if (n < Nreal) v = src[i];
    u16 hi = f2bf(v);
    u16 lo = f2bf(v - bf2f(hi));
    dst[(size_t)n * 2 * K + k] = hi;
    dst[(size_t)n * 2 * K + K + k] = lo;
}

// ---- FUSED split-bf16 MFMA GEMM, 128x128 tile ---------------------------
// Per 32-real-k window, stage {Ah,Al,Wh,Wl} once and compute all 3 split
// terms (AhWh + AhWl + AlWh) into the same acc: 16 b128 reads per 48 MFMA.
// LDS row = 128B: [hi 32 u16 | lo 32 u16]; lo sourced from col KL+k of the
// pair buffers (per-lane source of global_load_lds; LDS dest linear).
// 16B-chunk XOR swizzle (chunk ^= row&7) on source, undone on read (R1: 0
// conflicts).  kslice = REAL k per z-slice (multiple of 32).
__global__ __launch_bounds__(256) void gemm_mfma(const u16* __restrict__ Ap, int lda,
                                                 const u16* __restrict__ Wp, int ldw,
                                                 float* __restrict__ C, int ldc,
                                                 int KL, int kslice, size_t zstride,
                                                 int Nreal) {
    __shared__ u16 As[128][64];
    __shared__ u16 Ws[128][64];
    const int m0 = blockIdx.x * 128, n0 = blockIdx.y * 128;
    const int tid = threadIdx.x;
    const int wave = tid >> 6, lane = tid & 63;
    const int wm = (wave >> 1) * 64, wn = (wave & 1) * 64;
    const int lm = lane & 15, quad = lane >> 4;

    const int srow = lane >> 3;                 // == row & 7
    const int schunk = (lane & 7) ^ srow;       // swizzled logical chunk
    const int scol = (schunk < 4) ? schunk * 8 : KL + (schunk - 4) * 8;
    const int rloc = wave * 8 + srow;

    f32x4 acc[4][4] = {};

    const int kb0 = blockIdx.z * kslice;
    for (int ko = kb0; ko < kb0 + kslice; ko += 32) {
        #pragma unroll
        for (int p = 0; p < 4; p++) {
            int row = p * 32 + rloc;
            GLOAD_LDS16(Ap + (size_t)(m0 + row) * lda + ko + scol,
                        &As[p * 32 + wave * 8][0]);
            GLOAD_LDS16(Wp + (size_t)(n0 + row) * ldw + ko + scol,
                        &Ws[p * 32 + wave * 8][0]);
        }
        __syncthreads();
        const int ph = ((quad ^ lm) & 7) * 8;   // phys offset of logical 'quad'
        bf16x8 bh[4], bl[4];
        #pragma unroll
        for (int j = 0; j < 4; j++) {
            const u16* wr = &Ws[wn + j * 16 + lm][0];
            bh[j] = *(const bf16x8*)(wr + ph);
            bl[j] = *(const bf16x8*)(wr + (ph ^ 32));
        }
        #pragma unroll
        for (int i = 0; i < 4; i++) {
            const u16* ar = &As[wm + i * 16 + lm][0];
            bf16x8 ah = *(const bf16x8*)(ar + ph);
            bf16x8 al = *(const bf16x8*)(ar + (ph ^ 32));
            #pragma unroll
            for (int j = 0; j < 4; j++) {
                acc[i][j] = __builtin_amdgcn_mfma_f32_16x16x32_bf16(
                    ah, bh[j], acc[i][j], 0, 0, 0);
                acc[i][j] = __builtin_amdgcn_mfma_f32_16x16x32_bf16(
                    ah, bl[j], acc[i][j], 0, 0, 0);
                acc[i][j] = __builtin_amdgcn_mfma_f32_16x16x32_bf16(
                    al, bh[j], acc[i][j], 0, 0, 0);
            }
        }
        __syncthreads();
    }

    float* Cz = C + zstride * blockIdx.z;
    #pragma unroll
    for (int i = 0; i < 4; i++)
        #pragma unroll
        for (int j = 0; j < 4; j++)
            #pragma unroll
            for (int r = 0; r < 4; r++) {
                int mrow = m0 + wm + i * 16 + quad * 4 + r;   // C/D: row=quad*4+reg
                int ncol = n0 + wn + j * 16 + lm;             //      col=lane&15
                if (ncol < Nreal)
                    Cz[(size_t)mrow * ldc + ncol] = acc[i][j][r];
            }
}

// ------ reduce 8 x_proj partials -> dbl[R*48] -----------------------------
__global__ __launch_bounds__(256) void reduce_dbl_k(const float* __restrict__ pbuf,
                                                    float* __restrict__ dbl,
                                                    size_t RS) {
    size_t e = (size_t)blockIdx.x * 256 + threadIdx.x;
    float v = 0.0f;
    #pragma unroll
    for (int z = 0; z < 8; z++) v += pbuf[z * RS + e];
    dbl[e] = v;
}

// ------ reduce 4 out_proj partials + residual -> out[m, coff + n] ---------
__global__ __launch_bounds__(256) void reduce_out_k(const float* __restrict__ pbuf,
                                                    const float* __restrict__ res,
                                                    float* __restrict__ out,
                                                    int M, int coff) {
    int idx = blockIdx.x * 256 + threadIdx.x;
    int m = idx >> 6, n4 = (idx & 63) * 4;
    size_t e = (size_t)m * 256 + n4;
    size_t stride = (size_t)M * 256;
    float4 v = *(const float4*)(res + e);
    #pragma unroll
    for (int s = 0; s < 4; s++) {
        float4 p = *(const float4*)(pbuf + s * stride + e);
        v.x += p.x; v.y += p.y; v.z += p.z; v.w += p.w;
    }
    *(float4*)(out + (size_t)m * 512 + coff + n4) = v;
}

// ---- depthwise causal conv + SiLU; out = split-bf16 pair ----------------
__global__ __launch_bounds__(256) void conv_silu_k(const float* __restrict__ xz,
                                                   const float* __restrict__ cw,
                                                   const float* __restrict__ cb,
                                                   u16* __restrict__ xcp, int dir) {
    int bx = blockIdx.x;
    int dgrp = bx & 3;
    int rowgrp = bx >> 2;
    int l0 = (rowgrp & (SEQ / 4 - 1)) * 4;
    int b = rowgrp >> 9;
    int d = dgrp * 256 + threadIdx.x;

    int base = dir ? l0 : (l0 - 3);
    float x[7];
    #pragma unroll
    for (int i = 0; i < 7; i++) {
        int lr = base + i;
        x[i] = (lr >= 0 && lr < SEQ)
             ? xz[((size_t)b * SEQ + lr) * (2 * D_INNER) + d] : 0.0f;
    }
    float w0 = cw[d * 4 + 0], w1 = cw[d * 4 + 1];
    float w2 = cw[d * 4 + 2], w3 = cw[d * 4 + 3];
    float bias = cb[d];

    #pragma unroll
    for (int li = 0; li < 4; li++) {
        float acc;
        if (dir == 0)
            acc = bias + w0 * x[li] + w1 * x[li + 1] + w2 * x[li + 2] + w3 * x[li + 3];
        else
            acc = bias + w3 * x[li] + w2 * x[li + 1] + w1 * x[li + 2] + w0 * x[li + 3];
        float s = acc / (1.0f + __expf(-acc));
        u16 hi = f2bf(s);
        u16 lo = f2bf(s - bf2f(hi));
        size_t row = (size_t)b * SEQ + l0 + li;
        xcp[row * 2048 + d] = hi;
        xcp[row * 2048 + D_INNER + d] = lo;
    }
}

// ---- scan phase 1: per-chunk H (h_in=0) and P; dbl staged in LDS --------
// NO min-waves launch bound: R7 lesson — (256,8) forced VGPR 64->32 and the
// scan state spilled to scratch (WRITE_SIZE +50MB, VALUBusy 66->40, plus a
// ~150us scratch first-touch dispatch). Natural VGPR (<=64) already allows
// 8 waves/EU; nb=8 supplies the waves.
__global__ __launch_bounds__(256) void scan_p1(const u16* __restrict__ xcp,
                                               const float* __restrict__ dbl,
                                               const float* __restrict__ dtw,
                                               const float* __restrict__ dtb,
                                               const float* __restrict__ Alog,
                                               float* __restrict__ P,
                                               float* __restrict__ H,
                                               int nb, int TC, int dir) {
    __shared__ float sdbl[32 * 48];            // TC <= 32
    int t = threadIdx.x;
    int nblk4 = nb * 4;
    int c = blockIdx.x / nblk4;
    int rem = blockIdx.x - c * nblk4;
    int b = rem >> 2, dblk = rem & 3;
    int d = dblk * 256 + t;

    int lbase = dir ? (SEQ - (c + 1) * TC) : (c * TC);
    {
        const float* src = dbl + ((size_t)b * SEQ + lbase) * 48;
        int nf4 = TC * 12;
        for (int i = t; i < nf4; i += 256)
            *(float4*)&sdbl[i * 4] = *(const float4*)(src + i * 4);
    }

    float A2[16], wdt[16];
    const float* ap = Alog + (size_t)d * NST;
    const float* wp = dtw + (size_t)d * NST;
    #pragma unroll
    for (int n = 0; n < 16; n++) { A2[n] = -__expf(ap[n]) * LOG2E; wdt[n] = wp[n]; }
    float bdt = dtb[d];
    bool fast = true;
    #pragma unroll
    for (int n = 0; n < 16; n++)
        fast = fast && (fabsf(A2[n] - (n + 1) * A2[0]) < 1e-3f);

    float h[16] = {0,0,0,0,0,0,0,0,0,0,0,0,0,0,0,0};
    float S = 0.0f;

    int lstep = dir ? -1 : 1;
    int l0 = dir ? (lbase + TC - 1) : lbase;
    const u16* up = xcp + ((size_t)b * SEQ + l0) * 2048 + d;
    ptrdiff_t ups = (ptrdiff_t)lstep * 2048;
    const float* dr = sdbl + (dir ? (TC - 1) * 48 : 0);
    ptrdiff_t drs = (ptrdiff_t)lstep * 48;

    __syncthreads();

    auto body = [&](auto FC) {
        constexpr bool F = decltype(FC)::value;
        u16 uh = up[0], ul = up[D_INNER];          // current-step u
        #pragma unroll 2
        for (int s = 0; s < TC; s++) {
            u16 nh = up[ups], nl = up[ups + D_INNER];   // prefetch next step
            float dl[16], B[16];
            #pragma unroll
            for (int n = 0; n < 16; n += 4) {
                *(float4*)&dl[n] = *(const float4*)(dr + n);
                *(float4*)&B[n]  = *(const float4*)(dr + 16 + n);
            }
            float u = bf2f(uh) + bf2f(ul);
            float acc = bdt;
            #pragma unroll
            for (int n = 0; n < 16; n++) acc += dl[n] * wdt[n];
            float dt = (acc > 20.0f) ? acc : __logf(1.0f + __expf(acc));
            float dtu = dt * u;
            S += dt;
            float dA[16];
            if (F) {
                dA_pow(exp2f(A2[0] * dt), dA);
            } else {
                #pragma unroll
                for (int n = 0; n < 16; n++) dA[n] = exp2f(A2[n] * dt);
            }
            #pragma unroll
            for (int n = 0; n < 16; n++)
                h[n] = h[n] * dA[n] + dtu * B[n];
            uh = nh; ul = nl;
            dr += drs; up += ups;
        }
    };
    if (fast) body(TrueT{}); else body(FalseT{});

    size_t NCH = (size_t)nb * 16384;
    size_t base = (size_t)c * NCH + ((size_t)b * 1024 + d) * 16;
    float Pv[16];
    if (fast) {
        dA_pow(exp2f(A2[0] * S), Pv);
    } else {
        #pragma unroll
        for (int n = 0; n < 16; n++) Pv[n] = exp2f(A2[n] * S);
    }
    #pragma unroll
    for (int n = 0; n < 16; n += 4) {
        *(float4*)&H[base + n] = *(float4*)&h[n];
        *(float4*)&P[base + n] = *(float4*)&Pv[n];
    }
}

// ------- scan phase 2: combine chunk states; H repurposed as h_in --------
__global__ __launch_bounds__(256) void scan_p2(const float* __restrict__ P,
                                               float* __restrict__ H,
                                               int NCH, int NC) {
    size_t chain = (size_t)blockIdx.x * 256 + threadIdx.x;
    float h = 0.0f;
    for (int c = 0; c < NC; c++) {
        size_t i = (size_t)c * NCH + chain;
        float Hc = H[i], Pc = P[i];
        H[i] = h;
        h = Hc + Pc * h;
    }
}

// ---- scan phase 3: recurrence + silu(z) + y pair; dbl staged in LDS -----
__global__ __launch_bounds__(256) void scan_p3(const u16* __restrict__ xcp,
                                               const float* __restrict__ dbl,
                                               const float* __restrict__ dtw,
                                               const float* __restrict__ dtb,
                                               float* __restrict__ xz,
                                               const float* __restrict__ Alog,
                                               const float* __restrict__ Dp,
                                               const float* __restrict__ hin,
                                               int nb, int TC, int dir) {
    __shared__ float sdbl[32 * 48];
    int t = threadIdx.x;
    int nblk4 = nb * 4;
    int c = blockIdx.x / nblk4;
    int rem = blockIdx.x - c * nblk4;
    int b = rem >> 2, dblk = rem & 3;
    int d = dblk * 256 + t;

    int lbase = dir ? (SEQ - (c + 1) * TC) : (c * TC);
    {
        const float* src = dbl + ((size_t)b * SEQ + lbase) * 48;
        int nf4 = TC * 12;
        for (int i = t; i < nf4; i += 256)
            *(float4*)&sdbl[i * 4] = *(const float4*)(src + i * 4);
    }

    float A2[16], wdt[16];
    const float* ap = Alog + (size_t)d * NST;
    const float* wp = dtw + (size_t)d * NST;
    #pragma unroll
    for (int n = 0; n < 16; n++) { A2[n] = -__expf(ap[n]) * LOG2E; wdt[n] = wp[n]; }
    float bdt = dtb[d];
    float Dd = Dp[d];
    bool fast = true;
    #pragma unroll
    for (int n = 0; n < 16; n++)
        fast = fast && (fabsf(A2[n] - (n + 1) * A2[0]) < 1e-3f);

    size_t NCH = (size_t)nb * 16384;
    size_t base = (size_t)c * NCH + ((size_t)b * 1024 + d) * 16;
    float h[16];
    #pragma unroll
    for (int n = 0; n < 16; n += 4)
        *(float4*)&h[n] = *(const float4*)&hin[base + n];

    int lstep = dir ? -1 : 1;
    int l0 = dir ? (lbase + TC - 1) : lbase;
    size_t row0 = (size_t)b * SEQ + l0;
    const u16* up = xcp + row0 * 2048 + d;
    const float* zp = xz + row0 * 2048 + D_INNER + d;
    u16* yp = (u16*)(xz + row0 * 2048) + d;
    ptrdiff_t ups = (ptrdiff_t)lstep * 2048;
    ptrdiff_t zps = (ptrdiff_t)lstep * 2048;
    ptrdiff_t yps = (ptrdiff_t)lstep * 4096;   // u16 pitch of a 2048-float row
    const float* dr = sdbl + (dir ? (TC - 1) * 48 : 0);
    ptrdiff_t drs = (ptrdiff_t)lstep * 48;

    __syncthreads();

    auto body = [&](auto FC) {
        constexpr bool F = decltype(FC)::value;
        u16 uh = up[0], ul = up[D_INNER];
        float zc = *zp;
        #pragma unroll 2
        for (int s = 0; s < TC; s++) {
            u16 nh = up[ups], nl = up[ups + D_INNER];   // prefetch next step
            float zn = zp[zps];
            float dl[16], B[16], Cv[16];
            #pragma unroll
            for (int n = 0; n < 16; n += 4) {
                *(float4*)&dl[n] = *(const float4*)(dr + n);
                *(float4*)&B[n]  = *(const float4*)(dr + 16 + n);
                *(float4*)&Cv[n] = *(const float4*)(dr + 32 + n);
            }
            float u = bf2f(uh) + bf2f(ul);
            float acc = bdt;
            #pragma unroll
            for (int n = 0; n < 16; n++) acc += dl[n] * wdt[n];
            float dt = (acc > 20.0f) ? acc : __logf(1.0f + __expf(acc));
            float dtu = dt * u;
            float dA[16];
            if (F) {
                dA_pow(exp2f(A2[0] * dt), dA);
            } else {
                #pragma unroll
                for (int n = 0; n < 16; n++) dA[n] = exp2f(A2[n] * dt);
            }
            #pragma unroll
            for (int n = 0; n < 16; n++)
                h[n] = h[n] * dA[n] + dtu * B[n];

            float p0 = h[0]*Cv[0] + h[1]*Cv[1] + h[2]*Cv[2] + h[3]*Cv[3];
            float p1 = h[4]*Cv[4] + h[5]*Cv[5] + h[6]*Cv[6] + h[7]*Cv[7];
            float p2 = h[8]*Cv[8] + h[9]*Cv[9] + h[10]*Cv[10] + h[11]*Cv[11];
            float p3 = h[12]*Cv[12] + h[13]*Cv[13] + h[14]*Cv[14] + h[15]*Cv[15];

            float g = zc / (1.0f + __expf(-zc));
            float y = ((p0 + p1) + (p2 + p3) + u * Dd) * g;

            u16 hi = f2bf(y);
            yp[0] = hi;
            yp[D_INNER] = f2bf(y - bf2f(hi));

            uh = nh; ul = nl; zc = zn;
            dr += drs; up += ups; zp += zps; yp += yps;
        }
    };
    if (fast) body(TrueT{}); else body(FalseT{});
}

// ---------------- host launch --------------------------------------------
extern "C" void kernel_launch(void* const* d_in, const int* in_sizes, int n_in,
                              void* d_out, int out_size, void* d_ws, size_t ws_size,
                              hipStream_t stream) {
    const float* input = (const float*)d_in[0];
    float* out = (float*)d_out;

    const size_t wspl = (size_t)(2048 * 512 + 256 * 2048 + 128 * 2048) * 2;
    const int TC = 32;                 // R6 lesson: TC=16 doubles P/H+p2 cost
    // nb = batches per pass; try 8 (single pass/dir -> 2x wave supply for
    // scans), fall back if workspace is short.
    auto fits = [&](int nb_) {
        size_t ph2 = 2ull * (SEQ / TC) * nb_ * 16384 * 4;
        size_t per = (size_t)2048 * (256 + 2048 + 1024 + 48) * 4 * nb_;
        return ph2 + per + wspl <= ws_size;
    };
    int nb = 8;
    while (nb > 1 && !fits(nb)) nb >>= 1;
    const int NC = SEQ / TC;
    const int R = nb * SEQ;
    const int NCH = nb * 16384;
    const size_t PHsz = (size_t)NC * NCH;       // floats per P/H array

    float* P    = (float*)d_ws;        // xproj/out_proj partials / scan P
    float* H    = P + PHsz;
    float* xnf  = H + PHsz;
    float* xz   = xnf + (size_t)R * D_MODEL;
    float* xcyf = xz  + (size_t)R * 2 * D_INNER;
    float* dbl  = xcyf + (size_t)R * D_INNER;
    u16*  winp  = (u16*)(dbl + (size_t)R * 48);
    u16*  woutp = winp + (size_t)2048 * 512;
    u16*  xpp   = woutp + (size_t)256 * 2048;   // padded to 128 rows (zeros)
    u16*  xnp   = (u16*)xnf;
    u16*  xcp   = (u16*)xcyf;

    for (int dir = 0; dir < 2; dir++) {
        int o = 1 + dir * 10;
        const float* nw   = (const float*)d_in[o + 0];
        const float* win  = (const float*)d_in[o + 1];
        const float* cw   = (const float*)d_in[o + 2];
        const float* cb   = (const float*)d_in[o + 3];
        const float* xp   = (const float*)d_in[o + 4];
        const float* dtw  = (const float*)d_in[o + 5];
        const float* dtbv = (const float*)d_in[o + 6];
        const float* Alog = (const float*)d_in[o + 7];
        const float* Dp   = (const float*)d_in[o + 8];
        const float* wout = (const float*)d_in[o + 9];

        wsplit_k<<<2048 * 256 / 256, 256, 0, stream>>>(win, winp, D_MODEL);
        wsplit_k<<<256 * 1024 / 256, 256, 0, stream>>>(wout, woutp, D_INNER);
        wsplit_pad_k<<<128 * 1024 / 256, 256, 0, stream>>>(xp, xpp, D_INNER, 48);

        for (int b0 = 0; b0 < 8; b0 += nb) {
            const float* xin = input + (size_t)b0 * SEQ * D_MODEL;
            float* cout = out + (size_t)b0 * SEQ * 2 * D_MODEL;

            rmsnorm_k<<<R, 256, 0, stream>>>(xin, nw, xnp);
            // in_proj: xz[R,2048] = xn * win^T, KL=256 -> 8 fused windows
            gemm_mfma<<<dim3(R / 128, 16, 1), 256, 0, stream>>>(
                xnp, 512, winp, 512, xz, 2 * D_INNER, D_MODEL, D_MODEL, 0,
                2 * D_INNER);
            conv_silu_k<<<R, 256, 0, stream>>>(xz, cw, cb, xcp, dir);
            // x_proj: partials[8][R,48], KL=1024, split-K=8 -> 4 windows each
            gemm_mfma<<<dim3(R / 128, 1, 8), 256, 0, stream>>>(
                xcp, 2048, xpp, 2048, P, 48, D_INNER, D_INNER / 8,
                (size_t)R * 48, 48);
            reduce_dbl_k<<<R * 48 / 256, 256, 0, stream>>>(P, dbl, (size_t)R * 48);
            scan_p1<<<NC * nb * 4, 256, 0, stream>>>(
                xcp, dbl, dtw, dtbv, Alog, P, H, nb, TC, dir);
            scan_p2<<<NCH / 256, 256, 0, stream>>>(P, H, NCH, NC);
            scan_p3<<<NC * nb * 4, 256, 0, stream>>>(
                xcp, dbl, dtw, dtbv, xz, Alog, Dp, H, nb, TC, dir);
            // out_proj: y_pair * wout^T, KL=1024, split-K=4 -> 8 windows each
            gemm_mfma<<<dim3(R / 128, 2, 4), 256, 0, stream>>>(
                (const u16*)xz, 4096, woutp, 2048, P, 256, D_INNER, D_INNER / 4,
                (size_t)R * 256, 256);
            reduce_out_k<<<R * 64 / 256, 256, 0, stream>>>(
                P, xin, cout, R, dir * D_MODEL);
        }
    }
}

// Round 9
// 808.133 us; speedup vs baseline: 1.2865x; 1.0709x over previous
//
#include <hip/hip_runtime.h>

typedef unsigned short u16;
typedef __bf16 bf16x8 __attribute__((ext_vector_type(8)));
typedef float f32x4 __attribute__((ext_vector_type(4)));

#define D_MODEL 256
#define D_INNER 1024
#define NST     16
#define SEQ     2048
#define LOG2E   1.4426950408889634f

struct TrueT  { static constexpr bool value = true;  };
struct FalseT { static constexpr bool value = false; };

static __device__ __forceinline__ float bf2f(u16 u) {
    union { float f; unsigned v; } x; x.v = ((unsigned)u) << 16; return x.f;
}
static __device__ __forceinline__ u16 f2bf(float f) {
    union { float f; unsigned u; } x; x.f = f;
    unsigned r = 0x7FFF + ((x.u >> 16) & 1);
    return (u16)((x.u + r) >> 16);
}

// async global->LDS, 16B per lane, LDS dest = wave-uniform base + lane*16
#define GLOAD_LDS16(g, l)                                            \
    __builtin_amdgcn_global_load_lds(                                \
        (const __attribute__((address_space(1))) void*)(g),          \
        (__attribute__((address_space(3))) void*)(l), 16, 0, 0)

// dA[n] = e1^(n+1), n=0..15, via binary decomposition (16 muls, depth ~5)
static __device__ __forceinline__ void dA_pow(float e1, float* dA) {
    float e2 = e1 * e1, e3 = e2 * e1, e4 = e2 * e2;
    float e8 = e4 * e4, e12 = e8 * e4;
    dA[0] = e1;       dA[1] = e2;       dA[2] = e3;       dA[3] = e4;
    dA[4] = e4 * e1;  dA[5] = e4 * e2;  dA[6] = e4 * e3;  dA[7] = e8;
    dA[8] = e8 * e1;  dA[9] = e8 * e2;  dA[10] = e8 * e3; dA[11] = e12;
    dA[12] = e12 * e1; dA[13] = e12 * e2; dA[14] = e12 * e3; dA[15] = e8 * e8;
}

// ---- RMSNorm -> split-bf16 pair output: row = [256 hi | 256 lo] u16 ----
__global__ __launch_bounds__(256) void rmsnorm_k(const float* __restrict__ x,
                                                 const float* __restrict__ w,
                                                 u16* __restrict__ xnp) {
    int row = blockIdx.x, t = threadIdx.x;
    float v = x[(size_t)row * D_MODEL + t];
    float s = v * v;
    #pragma unroll
    for (int o = 32; o; o >>= 1) s += __shfl_xor(s, o, 64);
    __shared__ float red[4];
    if ((t & 63) == 0) red[t >> 6] = s;
    __syncthreads();
    float tot = red[0] + red[1] + red[2] + red[3];
    float scale = rsqrtf(tot * (1.0f / D_MODEL) + 1e-5f);
    float xv = v * scale * w[t];
    u16 hi = f2bf(xv);
    u16 lo = f2bf(xv - bf2f(hi));
    xnp[(size_t)row * 512 + t] = hi;
    xnp[(size_t)row * 512 + 256 + t] = lo;
}

// ---- weight split: src[N*K] f32 -> dst[N][2K] bf16 (hi | lo) -----------
__global__ __launch_bounds__(256) void wsplit_k(const float* __restrict__ src,
                                                u16* __restrict__ dst, int K) {
    int i = blockIdx.x * 256 + threadIdx.x;
    int n = i / K, k = i - n * K;
    float v = src[i];
    u16 hi = f2bf(v);
    u16 lo = f2bf(v - bf2f(hi));
    dst[(size_t)n * 2 * K + k] = hi;
    dst[(size_t)n * 2 * K + K + k] = lo;
}

// ---- weight split with zero-padded rows (for x_proj: 48 real -> 128) ----
__global__ __launch_bounds__(256) void wsplit_pad_k(const float* __restrict__ src,
                                                    u16* __restrict__ dst, int K,
                                                    int Nreal) {
    int i = blockIdx.x * 256 + threadIdx.x;
    int n = i / K, k = i - n * K;
    float v = 0.0f;
    if (n < Nreal) v = src[i];
    u16 hi = f2bf(v);
    u16 lo = f2bf(v - bf2f(hi));
    dst[(size_t)n * 2 * K + k] = hi;
    dst[(size_t)n * 2 * K + K + k] = lo;
}

// ---- FUSED split-bf16 MFMA GEMM, 128x128 tile ---------------------------
// Per 32-real-k window, stage {Ah,Al,Wh,Wl} once and compute all 3 split
// terms (AhWh + AhWl + AlWh) into the same acc: 16 b128 reads per 48 MFMA.
// LDS row = 128B: [hi 32 u16 | lo 32 u16]; lo sourced from col KL+k of the
// pair buffers (per-lane source of global_load_lds; LDS dest linear).
// 16B-chunk XOR swizzle (chunk ^= row&7) on source, undone on read (R1: 0
// conflicts).  kslice = REAL k per z-slice (multiple of 32).
__global__ __launch_bounds__(256) void gemm_mfma(const u16* __restrict__ Ap, int lda,
                                                 const u16* __restrict__ Wp, int ldw,
                                                 float* __restrict__ C, int ldc,
                                                 int KL, int kslice, size_t zstride,
                                                 int Nreal) {
    __shared__ u16 As[128][64];
    __shared__ u16 Ws[128][64];
    const int m0 = blockIdx.x * 128, n0 = blockIdx.y * 128;
    const int tid = threadIdx.x;
    const int wave = tid >> 6, lane = tid & 63;
    const int wm = (wave >> 1) * 64, wn = (wave & 1) * 64;
    const int lm = lane & 15, quad = lane >> 4;

    const int srow = lane >> 3;                 // == row & 7
    const int schunk = (lane & 7) ^ srow;       // swizzled logical chunk
    const int scol = (schunk < 4) ? schunk * 8 : KL + (schunk - 4) * 8;
    const int rloc = wave * 8 + srow;

    f32x4 acc[4][4] = {};

    const int kb0 = blockIdx.z * kslice;
    for (int ko = kb0; ko < kb0 + kslice; ko += 32) {
        #pragma unroll
        for (int p = 0; p < 4; p++) {
            int row = p * 32 + rloc;
            GLOAD_LDS16(Ap + (size_t)(m0 + row) * lda + ko + scol,
                        &As[p * 32 + wave * 8][0]);
            GLOAD_LDS16(Wp + (size_t)(n0 + row) * ldw + ko + scol,
                        &Ws[p * 32 + wave * 8][0]);
        }
        __syncthreads();
        const int ph = ((quad ^ lm) & 7) * 8;   // phys offset of logical 'quad'
        bf16x8 bh[4], bl[4];
        #pragma unroll
        for (int j = 0; j < 4; j++) {
            const u16* wr = &Ws[wn + j * 16 + lm][0];
            bh[j] = *(const bf16x8*)(wr + ph);
            bl[j] = *(const bf16x8*)(wr + (ph ^ 32));
        }
        #pragma unroll
        for (int i = 0; i < 4; i++) {
            const u16* ar = &As[wm + i * 16 + lm][0];
            bf16x8 ah = *(const bf16x8*)(ar + ph);
            bf16x8 al = *(const bf16x8*)(ar + (ph ^ 32));
            #pragma unroll
            for (int j = 0; j < 4; j++) {
                acc[i][j] = __builtin_amdgcn_mfma_f32_16x16x32_bf16(
                    ah, bh[j], acc[i][j], 0, 0, 0);
                acc[i][j] = __builtin_amdgcn_mfma_f32_16x16x32_bf16(
                    ah, bl[j], acc[i][j], 0, 0, 0);
                acc[i][j] = __builtin_amdgcn_mfma_f32_16x16x32_bf16(
                    al, bh[j], acc[i][j], 0, 0, 0);
            }
        }
        __syncthreads();
    }

    float* Cz = C + zstride * blockIdx.z;
    #pragma unroll
    for (int i = 0; i < 4; i++)
        #pragma unroll
        for (int j = 0; j < 4; j++)
            #pragma unroll
            for (int r = 0; r < 4; r++) {
                int mrow = m0 + wm + i * 16 + quad * 4 + r;   // C/D: row=quad*4+reg
                int ncol = n0 + wn + j * 16 + lm;             //      col=lane&15
                if (ncol < Nreal)
                    Cz[(size_t)mrow * ldc + ncol] = acc[i][j][r];
            }
}

// ------ reduce 8 x_proj partials -> dbl[R*48] -----------------------------
__global__ __launch_bounds__(256) void reduce_dbl_k(const float* __restrict__ pbuf,
                                                    float* __restrict__ dbl,
                                                    size_t RS) {
    size_t e = (size_t)blockIdx.x * 256 + threadIdx.x;
    float v = 0.0f;
    #pragma unroll
    for (int z = 0; z < 8; z++) v += pbuf[z * RS + e];
    dbl[e] = v;
}

// ------ reduce 4 out_proj partials + residual -> out[m, coff + n] ---------
__global__ __launch_bounds__(256) void reduce_out_k(const float* __restrict__ pbuf,
                                                    const float* __restrict__ res,
                                                    float* __restrict__ out,
                                                    int M, int coff) {
    int idx = blockIdx.x * 256 + threadIdx.x;
    int m = idx >> 6, n4 = (idx & 63) * 4;
    size_t e = (size_t)m * 256 + n4;
    size_t stride = (size_t)M * 256;
    float4 v = *(const float4*)(res + e);
    #pragma unroll
    for (int s = 0; s < 4; s++) {
        float4 p = *(const float4*)(pbuf + s * stride + e);
        v.x += p.x; v.y += p.y; v.z += p.z; v.w += p.w;
    }
    *(float4*)(out + (size_t)m * 512 + coff + n4) = v;
}

// ---- depthwise causal conv + SiLU; out = split-bf16 pair ----------------
__global__ __launch_bounds__(256) void conv_silu_k(const float* __restrict__ xz,
                                                   const float* __restrict__ cw,
                                                   const float* __restrict__ cb,
                                                   u16* __restrict__ xcp, int dir) {
    int bx = blockIdx.x;
    int dgrp = bx & 3;
    int rowgrp = bx >> 2;
    int l0 = (rowgrp & (SEQ / 4 - 1)) * 4;
    int b = rowgrp >> 9;
    int d = dgrp * 256 + threadIdx.x;

    int base = dir ? l0 : (l0 - 3);
    float x[7];
    #pragma unroll
    for (int i = 0; i < 7; i++) {
        int lr = base + i;
        x[i] = (lr >= 0 && lr < SEQ)
             ? xz[((size_t)b * SEQ + lr) * (2 * D_INNER) + d] : 0.0f;
    }
    float w0 = cw[d * 4 + 0], w1 = cw[d * 4 + 1];
    float w2 = cw[d * 4 + 2], w3 = cw[d * 4 + 3];
    float bias = cb[d];

    #pragma unroll
    for (int li = 0; li < 4; li++) {
        float acc;
        if (dir == 0)
            acc = bias + w0 * x[li] + w1 * x[li + 1] + w2 * x[li + 2] + w3 * x[li + 3];
        else
            acc = bias + w3 * x[li] + w2 * x[li + 1] + w1 * x[li + 2] + w0 * x[li + 3];
        float s = acc / (1.0f + __expf(-acc));
        u16 hi = f2bf(s);
        u16 lo = f2bf(s - bf2f(hi));
        size_t row = (size_t)b * SEQ + l0 + li;
        xcp[row * 2048 + d] = hi;
        xcp[row * 2048 + D_INNER + d] = lo;
    }
}

// ---- scan phase 1: per-chunk H (h_in=0) and S=sum(dt); dbl in LDS -------
// Chunk propagator P[n] = exp2(A2[n]*S) depends only on scalar S (each
// step's dA[n]=exp2(A2[n]*dt), product telescopes) -> store S (1 float),
// not P (16 floats): halves p1 writes, kills 33MB of workspace.
// No min-waves bound (R7: forcing 8/EU clamped VGPR->32 and spilled).
__global__ __launch_bounds__(256) void scan_p1(const u16* __restrict__ xcp,
                                               const float* __restrict__ dbl,
                                               const float* __restrict__ dtw,
                                               const float* __restrict__ dtb,
                                               const float* __restrict__ Alog,
                                               float* __restrict__ Sarr,
                                               float* __restrict__ H,
                                               int nb, int TC, int dir) {
    __shared__ float sdbl[32 * 48];            // TC <= 32
    int t = threadIdx.x;
    int nblk4 = nb * 4;
    int c = blockIdx.x / nblk4;
    int rem = blockIdx.x - c * nblk4;
    int b = rem >> 2, dblk = rem & 3;
    int d = dblk * 256 + t;

    int lbase = dir ? (SEQ - (c + 1) * TC) : (c * TC);
    {
        const float* src = dbl + ((size_t)b * SEQ + lbase) * 48;
        int nf4 = TC * 12;
        for (int i = t; i < nf4; i += 256)
            *(float4*)&sdbl[i * 4] = *(const float4*)(src + i * 4);
    }

    float A2[16], wdt[16];
    const float* ap = Alog + (size_t)d * NST;
    const float* wp = dtw + (size_t)d * NST;
    #pragma unroll
    for (int n = 0; n < 16; n++) { A2[n] = -__expf(ap[n]) * LOG2E; wdt[n] = wp[n]; }
    float bdt = dtb[d];
    bool fast = true;
    #pragma unroll
    for (int n = 0; n < 16; n++)
        fast = fast && (fabsf(A2[n] - (n + 1) * A2[0]) < 1e-3f);

    float h[16] = {0,0,0,0,0,0,0,0,0,0,0,0,0,0,0,0};
    float S = 0.0f;

    int lstep = dir ? -1 : 1;
    int l0 = dir ? (lbase + TC - 1) : lbase;
    const u16* up = xcp + ((size_t)b * SEQ + l0) * 2048 + d;
    ptrdiff_t ups = (ptrdiff_t)lstep * 2048;
    const float* dr = sdbl + (dir ? (TC - 1) * 48 : 0);
    ptrdiff_t drs = (ptrdiff_t)lstep * 48;

    __syncthreads();

    auto body = [&](auto FC) {
        constexpr bool F = decltype(FC)::value;
        u16 uh = up[0], ul = up[D_INNER];          // current-step u
        #pragma unroll 2
        for (int s = 0; s < TC; s++) {
            u16 nh = up[ups], nl = up[ups + D_INNER];   // prefetch next step
            float dl[16], B[16];
            #pragma unroll
            for (int n = 0; n < 16; n += 4) {
                *(float4*)&dl[n] = *(const float4*)(dr + n);
                *(float4*)&B[n]  = *(const float4*)(dr + 16 + n);
            }
            float u = bf2f(uh) + bf2f(ul);
            float acc = bdt;
            #pragma unroll
            for (int n = 0; n < 16; n++) acc += dl[n] * wdt[n];
            float dt = (acc > 20.0f) ? acc : __logf(1.0f + __expf(acc));
            float dtu = dt * u;
            S += dt;
            float dA[16];
            if (F) {
                dA_pow(exp2f(A2[0] * dt), dA);
            } else {
                #pragma unroll
                for (int n = 0; n < 16; n++) dA[n] = exp2f(A2[n] * dt);
            }
            #pragma unroll
            for (int n = 0; n < 16; n++)
                h[n] = h[n] * dA[n] + dtu * B[n];
            uh = nh; ul = nl;
            dr += drs; up += ups;
        }
    };
    if (fast) body(TrueT{}); else body(FalseT{});

    size_t NCH = (size_t)nb * 16384;
    size_t base = (size_t)c * NCH + ((size_t)b * 1024 + d) * 16;
    #pragma unroll
    for (int n = 0; n < 16; n += 4)
        *(float4*)&H[base + n] = *(float4*)&h[n];
    Sarr[(size_t)c * nb * 1024 + (size_t)b * 1024 + d] = S;
}

// ------- scan phase 2: combine chunk states; H repurposed as h_in --------
// P reconstructed from scalar S: Pc = exp2(A2[n] * S[c][b][d]).
__global__ __launch_bounds__(256) void scan_p2(const float* __restrict__ Sarr,
                                               float* __restrict__ H,
                                               const float* __restrict__ Alog,
                                               int nb, int NC) {
    size_t ch = (size_t)blockIdx.x * 256 + threadIdx.x;
    int n = (int)(ch & 15);
    int d = (int)((ch >> 4) & 1023);
    int bb = (int)(ch >> 14);
    float A2n = -__expf(Alog[(size_t)d * NST + n]) * LOG2E;
    size_t NCH = (size_t)nb * 16384;
    size_t snch = (size_t)nb * 1024;
    size_t sbase = (size_t)bb * 1024 + d;
    float h = 0.0f;
    for (int c = 0; c < NC; c++) {
        float Pc = exp2f(A2n * Sarr[c * snch + sbase]);
        size_t i = (size_t)c * NCH + ch;
        float Hc = H[i];
        H[i] = h;
        h = Hc + Pc * h;
    }
}

// ---- scan phase 3: recurrence + silu(z) + y pair; dbl staged in LDS -----
__global__ __launch_bounds__(256) void scan_p3(const u16* __restrict__ xcp,
                                               const float* __restrict__ dbl,
                                               const float* __restrict__ dtw,
                                               const float* __restrict__ dtb,
                                               float* __restrict__ xz,
                                               const float* __restrict__ Alog,
                                               const float* __restrict__ Dp,
                                               const float* __restrict__ hin,
                                               int nb, int TC, int dir) {
    __shared__ float sdbl[32 * 48];
    int t = threadIdx.x;
    int nblk4 = nb * 4;
    int c = blockIdx.x / nblk4;
    int rem = blockIdx.x - c * nblk4;
    int b = rem >> 2, dblk = rem & 3;
    int d = dblk * 256 + t;

    int lbase = dir ? (SEQ - (c + 1) * TC) : (c * TC);
    {
        const float* src = dbl + ((size_t)b * SEQ + lbase) * 48;
        int nf4 = TC * 12;
        for (int i = t; i < nf4; i += 256)
            *(float4*)&sdbl[i * 4] = *(const float4*)(src + i * 4);
    }

    float A2[16], wdt[16];
    const float* ap = Alog + (size_t)d * NST;
    const float* wp = dtw + (size_t)d * NST;
    #pragma unroll
    for (int n = 0; n < 16; n++) { A2[n] = -__expf(ap[n]) * LOG2E; wdt[n] = wp[n]; }
    float bdt = dtb[d];
    float Dd = Dp[d];
    bool fast = true;
    #pragma unroll
    for (int n = 0; n < 16; n++)
        fast = fast && (fabsf(A2[n] - (n + 1) * A2[0]) < 1e-3f);

    size_t NCH = (size_t)nb * 16384;
    size_t base = (size_t)c * NCH + ((size_t)b * 1024 + d) * 16;
    float h[16];
    #pragma unroll
    for (int n = 0; n < 16; n += 4)
        *(float4*)&h[n] = *(const float4*)&hin[base + n];

    int lstep = dir ? -1 : 1;
    int l0 = dir ? (lbase + TC - 1) : lbase;
    size_t row0 = (size_t)b * SEQ + l0;
    const u16* up = xcp + row0 * 2048 + d;
    const float* zp = xz + row0 * 2048 + D_INNER + d;
    u16* yp = (u16*)(xz + row0 * 2048) + d;
    ptrdiff_t ups = (ptrdiff_t)lstep * 2048;
    ptrdiff_t zps = (ptrdiff_t)lstep * 2048;
    ptrdiff_t yps = (ptrdiff_t)lstep * 4096;   // u16 pitch of a 2048-float row
    const float* dr = sdbl + (dir ? (TC - 1) * 48 : 0);
    ptrdiff_t drs = (ptrdiff_t)lstep * 48;

    __syncthreads();

    auto body = [&](auto FC) {
        constexpr bool F = decltype(FC)::value;
        u16 uh = up[0], ul = up[D_INNER];
        float zc = *zp;
        #pragma unroll 2
        for (int s = 0; s < TC; s++) {
            u16 nh = up[ups], nl = up[ups + D_INNER];   // prefetch next step
            float zn = zp[zps];
            float dl[16], B[16], Cv[16];
            #pragma unroll
            for (int n = 0; n < 16; n += 4) {
                *(float4*)&dl[n] = *(const float4*)(dr + n);
                *(float4*)&B[n]  = *(const float4*)(dr + 16 + n);
                *(float4*)&Cv[n] = *(const float4*)(dr + 32 + n);
            }
            float u = bf2f(uh) + bf2f(ul);
            float acc = bdt;
            #pragma unroll
            for (int n = 0; n < 16; n++) acc += dl[n] * wdt[n];
            float dt = (acc > 20.0f) ? acc : __logf(1.0f + __expf(acc));
            float dtu = dt * u;
            float dA[16];
            if (F) {
                dA_pow(exp2f(A2[0] * dt), dA);
            } else {
                #pragma unroll
                for (int n = 0; n < 16; n++) dA[n] = exp2f(A2[n] * dt);
            }
            #pragma unroll
            for (int n = 0; n < 16; n++)
                h[n] = h[n] * dA[n] + dtu * B[n];

            float p0 = h[0]*Cv[0] + h[1]*Cv[1] + h[2]*Cv[2] + h[3]*Cv[3];
            float p1 = h[4]*Cv[4] + h[5]*Cv[5] + h[6]*Cv[6] + h[7]*Cv[7];
            float p2 = h[8]*Cv[8] + h[9]*Cv[9] + h[10]*Cv[10] + h[11]*Cv[11];
            float p3 = h[12]*Cv[12] + h[13]*Cv[13] + h[14]*Cv[14] + h[15]*Cv[15];

            float g = zc / (1.0f + __expf(-zc));
            float y = ((p0 + p1) + (p2 + p3) + u * Dd) * g;

            u16 hi = f2bf(y);
            yp[0] = hi;
            yp[D_INNER] = f2bf(y - bf2f(hi));

            uh = nh; ul = nl; zc = zn;
            dr += drs; up += ups; zp += zps; yp += yps;
        }
    };
    if (fast) body(TrueT{}); else body(FalseT{});
}

// ---------------- host launch --------------------------------------------
extern "C" void kernel_launch(void* const* d_in, const int* in_sizes, int n_in,
                              void* d_out, int out_size, void* d_ws, size_t ws_size,
                              hipStream_t stream) {
    const float* input = (const float*)d_in[0];
    float* out = (float*)d_out;

    const size_t wspl = (size_t)(2048 * 512 + 256 * 2048 + 128 * 2048) * 2;
    const int TC = 32;
    // Workspace: H (NC*nb*16384 f32) + S (NC*nb*1024) + per-batch buffers.
    // x_proj partials alias H (consumed by reduce_dbl before p1 writes H);
    // out_proj partials (z=4: R*1024 f32) alias xcyf (xcp dead after p3).
    auto fits = [&](int nb_) {
        size_t ph = (size_t)(SEQ / TC) * nb_ * (16384 + 1024);
        size_t per = (size_t)2048 * (256 + 2048 + 1024 + 48) * nb_;
        return (ph + per) * 4 + wspl <= ws_size;
    };
    int nb = 8;
    while (nb > 1 && !fits(nb)) nb >>= 1;
    const int NC = SEQ / TC;
    const int R = nb * SEQ;
    const int NCH = nb * 16384;
    const size_t Hsz = (size_t)NC * NCH;

    float* H    = (float*)d_ws;        // chunk h / h_in; x_proj partials alias
    float* Sarr = H + Hsz;
    float* xnf  = Sarr + (size_t)NC * nb * 1024;
    float* xz   = xnf + (size_t)R * D_MODEL;
    float* xcyf = xz  + (size_t)R * 2 * D_INNER;   // xcp pair / out_proj partials
    float* dbl  = xcyf + (size_t)R * D_INNER;
    u16*  winp  = (u16*)(dbl + (size_t)R * 48);
    u16*  woutp = winp + (size_t)2048 * 512;
    u16*  xpp   = woutp + (size_t)256 * 2048;   // padded to 128 rows (zeros)
    u16*  xnp   = (u16*)xnf;
    u16*  xcp   = (u16*)xcyf;

    for (int dir = 0; dir < 2; dir++) {
        int o = 1 + dir * 10;
        const float* nw   = (const float*)d_in[o + 0];
        const float* win  = (const float*)d_in[o + 1];
        const float* cw   = (const float*)d_in[o + 2];
        const float* cb   = (const float*)d_in[o + 3];
        const float* xp   = (const float*)d_in[o + 4];
        const float* dtw  = (const float*)d_in[o + 5];
        const float* dtbv = (const float*)d_in[o + 6];
        const float* Alog = (const float*)d_in[o + 7];
        const float* Dp   = (const float*)d_in[o + 8];
        const float* wout = (const float*)d_in[o + 9];

        wsplit_k<<<2048 * 256 / 256, 256, 0, stream>>>(win, winp, D_MODEL);
        wsplit_k<<<256 * 1024 / 256, 256, 0, stream>>>(wout, woutp, D_INNER);
        wsplit_pad_k<<<128 * 1024 / 256, 256, 0, stream>>>(xp, xpp, D_INNER, 48);

        for (int b0 = 0; b0 < 8; b0 += nb) {
            const float* xin = input + (size_t)b0 * SEQ * D_MODEL;
            float* cout = out + (size_t)b0 * SEQ * 2 * D_MODEL;

            rmsnorm_k<<<R, 256, 0, stream>>>(xin, nw, xnp);
            // in_proj: xz[R,2048] = xn * win^T, KL=256 -> 8 fused windows
            gemm_mfma<<<dim3(R / 128, 16, 1), 256, 0, stream>>>(
                xnp, 512, winp, 512, xz, 2 * D_INNER, D_MODEL, D_MODEL, 0,
                2 * D_INNER);
            conv_silu_k<<<R, 256, 0, stream>>>(xz, cw, cb, xcp, dir);
            // x_proj: partials[8][R,48] -> H region, KL=1024, split-K=8
            gemm_mfma<<<dim3(R / 128, 1, 8), 256, 0, stream>>>(
                xcp, 2048, xpp, 2048, H, 48, D_INNER, D_INNER / 8,
                (size_t)R * 48, 48);
            reduce_dbl_k<<<R * 48 / 256, 256, 0, stream>>>(H, dbl, (size_t)R * 48);
            scan_p1<<<NC * nb * 4, 256, 0, stream>>>(
                xcp, dbl, dtw, dtbv, Alog, Sarr, H, nb, TC, dir);
            scan_p2<<<NCH / 256, 256, 0, stream>>>(Sarr, H, Alog, nb, NC);
            scan_p3<<<NC * nb * 4, 256, 0, stream>>>(
                xcp, dbl, dtw, dtbv, xz, Alog, Dp, H, nb, TC, dir);
            // out_proj: y_pair * wout^T, partials -> xcyf (xcp dead), z=4
            gemm_mfma<<<dim3(R / 128, 2, 4), 256, 0, stream>>>(
                (const u16*)xz, 4096, woutp, 2048, xcyf, 256, D_INNER,
                D_INNER / 4, (size_t)R * 256, 256);
            reduce_out_k<<<R * 64 / 256, 256, 0, stream>>>(
                xcyf, xin, cout, R, dir * D_MODEL);
        }
    }
}

// Round 10
// 785.151 us; speedup vs baseline: 1.3241x; 1.0293x over previous
//
#include <hip/hip_runtime.h>

typedef unsigned short u16;
typedef __bf16 bf16x8 __attribute__((ext_vector_type(8)));
typedef float f32x4 __attribute__((ext_vector_type(4)));

#define D_MODEL 256
#define D_INNER 1024
#define NST     16
#define SEQ     2048
#define LOG2E   1.4426950408889634f

struct TrueT  { static constexpr bool value = true;  };
struct FalseT { static constexpr bool value = false; };

static __device__ __forceinline__ float bf2f(u16 u) {
    union { float f; unsigned v; } x; x.v = ((unsigned)u) << 16; return x.f;
}
static __device__ __forceinline__ u16 f2bf(float f) {
    union { float f; unsigned u; } x; x.f = f;
    unsigned r = 0x7FFF + ((x.u >> 16) & 1);
    return (u16)((x.u + r) >> 16);
}

// async global->LDS, 16B per lane, LDS dest = wave-uniform base + lane*16
#define GLOAD_LDS16(g, l)                                            \
    __builtin_amdgcn_global_load_lds(                                \
        (const __attribute__((address_space(1))) void*)(g),          \
        (__attribute__((address_space(3))) void*)(l), 16, 0, 0)

// dA[n] = e1^(n+1), n=0..15, via binary decomposition (16 muls, depth ~5)
static __device__ __forceinline__ void dA_pow(float e1, float* dA) {
    float e2 = e1 * e1, e3 = e2 * e1, e4 = e2 * e2;
    float e8 = e4 * e4, e12 = e8 * e4;
    dA[0] = e1;       dA[1] = e2;       dA[2] = e3;       dA[3] = e4;
    dA[4] = e4 * e1;  dA[5] = e4 * e2;  dA[6] = e4 * e3;  dA[7] = e8;
    dA[8] = e8 * e1;  dA[9] = e8 * e2;  dA[10] = e8 * e3; dA[11] = e12;
    dA[12] = e12 * e1; dA[13] = e12 * e2; dA[14] = e12 * e3; dA[15] = e8 * e8;
}

// ---- RMSNorm -> split-bf16 pair output: row = [256 hi | 256 lo] u16 ----
__global__ __launch_bounds__(256) void rmsnorm_k(const float* __restrict__ x,
                                                 const float* __restrict__ w,
                                                 u16* __restrict__ xnp) {
    int row = blockIdx.x, t = threadIdx.x;
    float v = x[(size_t)row * D_MODEL + t];
    float s = v * v;
    #pragma unroll
    for (int o = 32; o; o >>= 1) s += __shfl_xor(s, o, 64);
    __shared__ float red[4];
    if ((t & 63) == 0) red[t >> 6] = s;
    __syncthreads();
    float tot = red[0] + red[1] + red[2] + red[3];
    float scale = rsqrtf(tot * (1.0f / D_MODEL) + 1e-5f);
    float xv = v * scale * w[t];
    u16 hi = f2bf(xv);
    u16 lo = f2bf(xv - bf2f(hi));
    xnp[(size_t)row * 512 + t] = hi;
    xnp[(size_t)row * 512 + 256 + t] = lo;
}

// ---- weight split: src[N*K] f32 -> dst[N][2K] bf16 (hi | lo) -----------
__global__ __launch_bounds__(256) void wsplit_k(const float* __restrict__ src,
                                                u16* __restrict__ dst, int K) {
    int i = blockIdx.x * 256 + threadIdx.x;
    int n = i / K, k = i - n * K;
    float v = src[i];
    u16 hi = f2bf(v);
    u16 lo = f2bf(v - bf2f(hi));
    dst[(size_t)n * 2 * K + k] = hi;
    dst[(size_t)n * 2 * K + K + k] = lo;
}

// ---- weight split with zero-padded rows (for x_proj: 48 real -> 128) ----
__global__ __launch_bounds__(256) void wsplit_pad_k(const float* __restrict__ src,
                                                    u16* __restrict__ dst, int K,
                                                    int Nreal) {
    int i = blockIdx.x * 256 + threadIdx.x;
    int n = i / K, k = i - n * K;
    float v = 0.0f;
    if (n < Nreal) v = src[i];
    u16 hi = f2bf(v);
    u16 lo = f2bf(v - bf2f(hi));
    dst[(size_t)n * 2 * K + k] = hi;
    dst[(size_t)n * 2 * K + K + k] = lo;
}

// ---- FUSED split-bf16 MFMA GEMM, 128x128 tile ---------------------------
// Per 32-real-k window, stage {Ah,Al,Wh,Wl} once and compute all 3 split
// terms (AhWh + AhWl + AlWh) into the same acc: 16 b128 reads per 48 MFMA.
// kslice = REAL k per z-slice (multiple of 32).
__global__ __launch_bounds__(256) void gemm_mfma(const u16* __restrict__ Ap, int lda,
                                                 const u16* __restrict__ Wp, int ldw,
                                                 float* __restrict__ C, int ldc,
                                                 int KL, int kslice, size_t zstride,
                                                 int Nreal) {
    __shared__ u16 As[128][64];
    __shared__ u16 Ws[128][64];
    const int m0 = blockIdx.x * 128, n0 = blockIdx.y * 128;
    const int tid = threadIdx.x;
    const int wave = tid >> 6, lane = tid & 63;
    const int wm = (wave >> 1) * 64, wn = (wave & 1) * 64;
    const int lm = lane & 15, quad = lane >> 4;

    const int srow = lane >> 3;                 // == row & 7
    const int schunk = (lane & 7) ^ srow;       // swizzled logical chunk
    const int scol = (schunk < 4) ? schunk * 8 : KL + (schunk - 4) * 8;
    const int rloc = wave * 8 + srow;

    f32x4 acc[4][4] = {};

    const int kb0 = blockIdx.z * kslice;
    for (int ko = kb0; ko < kb0 + kslice; ko += 32) {
        #pragma unroll
        for (int p = 0; p < 4; p++) {
            int row = p * 32 + rloc;
            GLOAD_LDS16(Ap + (size_t)(m0 + row) * lda + ko + scol,
                        &As[p * 32 + wave * 8][0]);
            GLOAD_LDS16(Wp + (size_t)(n0 + row) * ldw + ko + scol,
                        &Ws[p * 32 + wave * 8][0]);
        }
        __syncthreads();
        const int ph = ((quad ^ lm) & 7) * 8;   // phys offset of logical 'quad'
        bf16x8 bh[4], bl[4];
        #pragma unroll
        for (int j = 0; j < 4; j++) {
            const u16* wr = &Ws[wn + j * 16 + lm][0];
            bh[j] = *(const bf16x8*)(wr + ph);
            bl[j] = *(const bf16x8*)(wr + (ph ^ 32));
        }
        #pragma unroll
        for (int i = 0; i < 4; i++) {
            const u16* ar = &As[wm + i * 16 + lm][0];
            bf16x8 ah = *(const bf16x8*)(ar + ph);
            bf16x8 al = *(const bf16x8*)(ar + (ph ^ 32));
            #pragma unroll
            for (int j = 0; j < 4; j++) {
                acc[i][j] = __builtin_amdgcn_mfma_f32_16x16x32_bf16(
                    ah, bh[j], acc[i][j], 0, 0, 0);
                acc[i][j] = __builtin_amdgcn_mfma_f32_16x16x32_bf16(
                    ah, bl[j], acc[i][j], 0, 0, 0);
                acc[i][j] = __builtin_amdgcn_mfma_f32_16x16x32_bf16(
                    al, bh[j], acc[i][j], 0, 0, 0);
            }
        }
        __syncthreads();
    }

    float* Cz = C + zstride * blockIdx.z;
    #pragma unroll
    for (int i = 0; i < 4; i++)
        #pragma unroll
        for (int j = 0; j < 4; j++)
            #pragma unroll
            for (int r = 0; r < 4; r++) {
                int mrow = m0 + wm + i * 16 + quad * 4 + r;   // C/D: row=quad*4+reg
                int ncol = n0 + wn + j * 16 + lm;             //      col=lane&15
                if (ncol < Nreal)
                    Cz[(size_t)mrow * ldc + ncol] = acc[i][j][r];
            }
}

// ------ reduce 8 x_proj partials -> dbl[R*48] -----------------------------
__global__ __launch_bounds__(256) void reduce_dbl_k(const float* __restrict__ pbuf,
                                                    float* __restrict__ dbl,
                                                    size_t RS) {
    size_t e = (size_t)blockIdx.x * 256 + threadIdx.x;
    float v = 0.0f;
    #pragma unroll
    for (int z = 0; z < 8; z++) v += pbuf[z * RS + e];
    dbl[e] = v;
}

// ------ reduce ns out_proj partials + residual -> out[m, coff + n] --------
__global__ __launch_bounds__(256) void reduce_out_k(const float* __restrict__ pbuf,
                                                    const float* __restrict__ res,
                                                    float* __restrict__ out,
                                                    int M, int coff, int ns) {
    int idx = blockIdx.x * 256 + threadIdx.x;
    int m = idx >> 6, n4 = (idx & 63) * 4;
    size_t e = (size_t)m * 256 + n4;
    size_t stride = (size_t)M * 256;
    float4 v = *(const float4*)(res + e);
    for (int s = 0; s < ns; s++) {
        float4 p = *(const float4*)(pbuf + s * stride + e);
        v.x += p.x; v.y += p.y; v.z += p.z; v.w += p.w;
    }
    *(float4*)(out + (size_t)m * 512 + coff + n4) = v;
}

// ---- depthwise causal conv + SiLU; out = split-bf16 pair ----------------
__global__ __launch_bounds__(256) void conv_silu_k(const float* __restrict__ xz,
                                                   const float* __restrict__ cw,
                                                   const float* __restrict__ cb,
                                                   u16* __restrict__ xcp, int dir) {
    int bx = blockIdx.x;
    int dgrp = bx & 3;
    int rowgrp = bx >> 2;
    int l0 = (rowgrp & (SEQ / 4 - 1)) * 4;
    int b = rowgrp >> 9;
    int d = dgrp * 256 + threadIdx.x;

    int base = dir ? l0 : (l0 - 3);
    float x[7];
    #pragma unroll
    for (int i = 0; i < 7; i++) {
        int lr = base + i;
        x[i] = (lr >= 0 && lr < SEQ)
             ? xz[((size_t)b * SEQ + lr) * (2 * D_INNER) + d] : 0.0f;
    }
    float w0 = cw[d * 4 + 0], w1 = cw[d * 4 + 1];
    float w2 = cw[d * 4 + 2], w3 = cw[d * 4 + 3];
    float bias = cb[d];

    #pragma unroll
    for (int li = 0; li < 4; li++) {
        float acc;
        if (dir == 0)
            acc = bias + w0 * x[li] + w1 * x[li + 1] + w2 * x[li + 2] + w3 * x[li + 3];
        else
            acc = bias + w3 * x[li] + w2 * x[li + 1] + w1 * x[li + 2] + w0 * x[li + 3];
        float s = acc / (1.0f + __expf(-acc));
        u16 hi = f2bf(s);
        u16 lo = f2bf(s - bf2f(hi));
        size_t row = (size_t)b * SEQ + l0 + li;
        xcp[row * 2048 + d] = hi;
        xcp[row * 2048 + D_INNER + d] = lo;
    }
}

// ---- scan phase 1: per-chunk H (h_in=0) and S=sum(dt); dbl in LDS -------
// DT: additionally store per-step dt (f32) for p3 to reuse.
// No min-waves bound (R7: forcing 8/EU clamped VGPR->32 and spilled).
template <bool DT>
__global__ __launch_bounds__(256) void scan_p1(const u16* __restrict__ xcp,
                                               const float* __restrict__ dbl,
                                               const float* __restrict__ dtw,
                                               const float* __restrict__ dtb,
                                               const float* __restrict__ Alog,
                                               float* __restrict__ Sarr,
                                               float* __restrict__ H,
                                               float* __restrict__ dtbuf,
                                               int nb, int TC, int dir) {
    __shared__ float sdbl[32 * 48];            // TC <= 32
    int t = threadIdx.x;
    int nblk4 = nb * 4;
    int c = blockIdx.x / nblk4;
    int rem = blockIdx.x - c * nblk4;
    int b = rem >> 2, dblk = rem & 3;
    int d = dblk * 256 + t;

    int lbase = dir ? (SEQ - (c + 1) * TC) : (c * TC);
    {
        const float* src = dbl + ((size_t)b * SEQ + lbase) * 48;
        int nf4 = TC * 12;
        for (int i = t; i < nf4; i += 256)
            *(float4*)&sdbl[i * 4] = *(const float4*)(src + i * 4);
    }

    float A2[16], wdt[16];
    const float* ap = Alog + (size_t)d * NST;
    const float* wp = dtw + (size_t)d * NST;
    #pragma unroll
    for (int n = 0; n < 16; n++) { A2[n] = -__expf(ap[n]) * LOG2E; wdt[n] = wp[n]; }
    float bdt = dtb[d];
    bool fast = true;
    #pragma unroll
    for (int n = 0; n < 16; n++)
        fast = fast && (fabsf(A2[n] - (n + 1) * A2[0]) < 1e-3f);

    float h[16] = {0,0,0,0,0,0,0,0,0,0,0,0,0,0,0,0};
    float S = 0.0f;

    int lstep = dir ? -1 : 1;
    int l0 = dir ? (lbase + TC - 1) : lbase;
    size_t row0 = (size_t)b * SEQ + l0;
    const u16* up = xcp + row0 * 2048 + d;
    ptrdiff_t ups = (ptrdiff_t)lstep * 2048;
    float* dtp = DT ? (dtbuf + row0 * 1024 + d) : nullptr;
    ptrdiff_t dps = (ptrdiff_t)lstep * 1024;
    const float* dr = sdbl + (dir ? (TC - 1) * 48 : 0);
    ptrdiff_t drs = (ptrdiff_t)lstep * 48;

    __syncthreads();

    auto body = [&](auto FC) {
        constexpr bool F = decltype(FC)::value;
        u16 uh = up[0], ul = up[D_INNER];          // current-step u
        #pragma unroll 2
        for (int s = 0; s < TC; s++) {
            u16 nh = up[ups], nl = up[ups + D_INNER];   // prefetch next step
            float dl[16], B[16];
            #pragma unroll
            for (int n = 0; n < 16; n += 4) {
                *(float4*)&dl[n] = *(const float4*)(dr + n);
                *(float4*)&B[n]  = *(const float4*)(dr + 16 + n);
            }
            float u = bf2f(uh) + bf2f(ul);
            float acc = bdt;
            #pragma unroll
            for (int n = 0; n < 16; n++) acc += dl[n] * wdt[n];
            float dt = (acc > 20.0f) ? acc : __logf(1.0f + __expf(acc));
            if (DT) { dtp[0] = dt; dtp += dps; }
            float dtu = dt * u;
            S += dt;
            float dA[16];
            if (F) {
                dA_pow(exp2f(A2[0] * dt), dA);
            } else {
                #pragma unroll
                for (int n = 0; n < 16; n++) dA[n] = exp2f(A2[n] * dt);
            }
            #pragma unroll
            for (int n = 0; n < 16; n++)
                h[n] = h[n] * dA[n] + dtu * B[n];
            uh = nh; ul = nl;
            dr += drs; up += ups;
        }
    };
    if (fast) body(TrueT{}); else body(FalseT{});

    size_t NCH = (size_t)nb * 16384;
    size_t base = (size_t)c * NCH + ((size_t)b * 1024 + d) * 16;
    #pragma unroll
    for (int n = 0; n < 16; n += 4)
        *(float4*)&H[base + n] = *(float4*)&h[n];
    Sarr[(size_t)c * nb * 1024 + (size_t)b * 1024 + d] = S;
}

// ------- scan phase 2: combine chunk states; H repurposed as h_in --------
// P reconstructed from scalar S: Pc = exp2(A2[n] * S[c][b][d]).
__global__ __launch_bounds__(256) void scan_p2(const float* __restrict__ Sarr,
                                               float* __restrict__ H,
                                               const float* __restrict__ Alog,
                                               int nb, int NC) {
    size_t ch = (size_t)blockIdx.x * 256 + threadIdx.x;
    int n = (int)(ch & 15);
    int d = (int)((ch >> 4) & 1023);
    int bb = (int)(ch >> 14);
    float A2n = -__expf(Alog[(size_t)d * NST + n]) * LOG2E;
    size_t NCH = (size_t)nb * 16384;
    size_t snch = (size_t)nb * 1024;
    size_t sbase = (size_t)bb * 1024 + d;
    float h = 0.0f;
    for (int c = 0; c < NC; c++) {
        float Pc = exp2f(A2n * Sarr[c * snch + sbase]);
        size_t i = (size_t)c * NCH + ch;
        float Hc = H[i];
        H[i] = h;
        h = Hc + Pc * h;
    }
}

// ---- scan phase 3: recurrence + silu(z) + y pair --------------------------
// DT: dt read from dtbuf (computed in p1) -> skips dl staging + 16-FMA dot
// + softplus per step; stages only B,C (32 floats/row).
template <bool DT>
__global__ __launch_bounds__(256) void scan_p3(const u16* __restrict__ xcp,
                                               const float* __restrict__ dbl,
                                               const float* __restrict__ dtw,
                                               const float* __restrict__ dtb,
                                               float* __restrict__ xz,
                                               const float* __restrict__ Alog,
                                               const float* __restrict__ Dp,
                                               const float* __restrict__ hin,
                                               const float* __restrict__ dtbuf,
                                               int nb, int TC, int dir) {
    constexpr int W = DT ? 32 : 48;
    __shared__ float sdbl[32 * 48];
    int t = threadIdx.x;
    int nblk4 = nb * 4;
    int c = blockIdx.x / nblk4;
    int rem = blockIdx.x - c * nblk4;
    int b = rem >> 2, dblk = rem & 3;
    int d = dblk * 256 + t;

    int lbase = dir ? (SEQ - (c + 1) * TC) : (c * TC);
    {
        const float* src = dbl + ((size_t)b * SEQ + lbase) * 48 + (DT ? 16 : 0);
        int nf4 = TC * (W / 4);
        for (int i = t; i < nf4; i += 256) {
            int row = i / (W / 4), c4 = i - row * (W / 4);
            *(float4*)&sdbl[row * W + c4 * 4] =
                *(const float4*)(src + row * 48 + c4 * 4);
        }
    }

    float A2[16], wdt[16];
    const float* ap = Alog + (size_t)d * NST;
    const float* wp = dtw + (size_t)d * NST;
    #pragma unroll
    for (int n = 0; n < 16; n++) { A2[n] = -__expf(ap[n]) * LOG2E; wdt[n] = wp[n]; }
    float bdt = dtb[d];
    float Dd = Dp[d];
    bool fast = true;
    #pragma unroll
    for (int n = 0; n < 16; n++)
        fast = fast && (fabsf(A2[n] - (n + 1) * A2[0]) < 1e-3f);

    size_t NCH = (size_t)nb * 16384;
    size_t base = (size_t)c * NCH + ((size_t)b * 1024 + d) * 16;
    float h[16];
    #pragma unroll
    for (int n = 0; n < 16; n += 4)
        *(float4*)&h[n] = *(const float4*)&hin[base + n];

    int lstep = dir ? -1 : 1;
    int l0 = dir ? (lbase + TC - 1) : lbase;
    size_t row0 = (size_t)b * SEQ + l0;
    const u16* up = xcp + row0 * 2048 + d;
    const float* zp = xz + row0 * 2048 + D_INNER + d;
    u16* yp = (u16*)(xz + row0 * 2048) + d;
    const float* dtp = DT ? (dtbuf + row0 * 1024 + d) : nullptr;
    ptrdiff_t ups = (ptrdiff_t)lstep * 2048;
    ptrdiff_t zps = (ptrdiff_t)lstep * 2048;
    ptrdiff_t yps = (ptrdiff_t)lstep * 4096;   // u16 pitch of a 2048-float row
    ptrdiff_t dps = (ptrdiff_t)lstep * 1024;
    const float* dr = sdbl + (dir ? (TC - 1) * W : 0);
    ptrdiff_t drs = (ptrdiff_t)lstep * W;

    __syncthreads();

    auto body = [&](auto FC) {
        constexpr bool F = decltype(FC)::value;
        u16 uh = up[0], ul = up[D_INNER];
        float zc = *zp;
        float dtc = DT ? dtp[0] : 0.0f;
        #pragma unroll 2
        for (int s = 0; s < TC; s++) {
            u16 nh = up[ups], nl = up[ups + D_INNER];   // prefetch next step
            float zn = zp[zps];
            float dtn = DT ? dtp[dps] : 0.0f;
            float B[16], Cv[16];
            #pragma unroll
            for (int n = 0; n < 16; n += 4) {
                *(float4*)&B[n]  = *(const float4*)(dr + (DT ? 0 : 16) + n);
                *(float4*)&Cv[n] = *(const float4*)(dr + (DT ? 16 : 32) + n);
            }
            float u = bf2f(uh) + bf2f(ul);
            float dt;
            if (DT) {
                dt = dtc;
            } else {
                float dl[16];
                #pragma unroll
                for (int n = 0; n < 16; n += 4)
                    *(float4*)&dl[n] = *(const float4*)(dr + n);
                float acc = bdt;
                #pragma unroll
                for (int n = 0; n < 16; n++) acc += dl[n] * wdt[n];
                dt = (acc > 20.0f) ? acc : __logf(1.0f + __expf(acc));
            }
            float dtu = dt * u;
            float dA[16];
            if (F) {
                dA_pow(exp2f(A2[0] * dt), dA);
            } else {
                #pragma unroll
                for (int n = 0; n < 16; n++) dA[n] = exp2f(A2[n] * dt);
            }
            #pragma unroll
            for (int n = 0; n < 16; n++)
                h[n] = h[n] * dA[n] + dtu * B[n];

            float p0 = h[0]*Cv[0] + h[1]*Cv[1] + h[2]*Cv[2] + h[3]*Cv[3];
            float p1 = h[4]*Cv[4] + h[5]*Cv[5] + h[6]*Cv[6] + h[7]*Cv[7];
            float p2 = h[8]*Cv[8] + h[9]*Cv[9] + h[10]*Cv[10] + h[11]*Cv[11];
            float p3 = h[12]*Cv[12] + h[13]*Cv[13] + h[14]*Cv[14] + h[15]*Cv[15];

            float g = zc / (1.0f + __expf(-zc));
            float y = ((p0 + p1) + (p2 + p3) + u * Dd) * g;

            u16 hi = f2bf(y);
            yp[0] = hi;
            yp[D_INNER] = f2bf(y - bf2f(hi));

            uh = nh; ul = nl; zc = zn; dtc = dtn;
            dr += drs; up += ups; zp += zps; yp += yps;
            if (DT) dtp += dps;
        }
    };
    if (fast) body(TrueT{}); else body(FalseT{});
}

// ---------------- host launch --------------------------------------------
extern "C" void kernel_launch(void* const* d_in, const int* in_sizes, int n_in,
                              void* d_out, int out_size, void* d_ws, size_t ws_size,
                              hipStream_t stream) {
    const float* input = (const float*)d_in[0];
    float* out = (float*)d_out;

    const size_t wspl = (size_t)(2048 * 512 + 256 * 2048 + 128 * 2048) * 2;
    const int TC = 32;
    const int NC = SEQ / TC;
    // Workspace: H + S (+ dt cache if it fits) + per-batch buffers.
    // x_proj partials alias H; out_proj partials (z=2) alias xcyf.
    auto fitsz = [&](int nb_, bool dt_) {
        size_t fl = (size_t)NC * nb_ * (16384 + 1024)
                  + (dt_ ? (size_t)nb_ * SEQ * 1024 : 0)
                  + (size_t)nb_ * SEQ * (256 + 2048 + 1024 + 48);
        return fl * 4 + wspl <= ws_size;
    };
    int nb = 8; bool usedt = true;
    if (!fitsz(8, true)) {
        if (fitsz(8, false)) { nb = 8; usedt = false; }
        else if (fitsz(4, true)) { nb = 4; usedt = true; }
        else { usedt = false; nb = 4; while (nb > 1 && !fitsz(nb, false)) nb >>= 1; }
    }
    const int R = nb * SEQ;
    const int NCH = nb * 16384;
    const size_t Hsz = (size_t)NC * NCH;

    float* H    = (float*)d_ws;        // chunk h / h_in; x_proj partials alias
    float* Sarr = H + Hsz;
    float* dtbf = Sarr + (size_t)NC * nb * 1024;
    float* xnf  = dtbf + (usedt ? (size_t)R * 1024 : 0);
    float* xz   = xnf + (size_t)R * D_MODEL;
    float* xcyf = xz  + (size_t)R * 2 * D_INNER;   // xcp pair / out_proj partials
    float* dbl  = xcyf + (size_t)R * D_INNER;
    u16*  winp  = (u16*)(dbl + (size_t)R * 48);
    u16*  woutp = winp + (size_t)2048 * 512;
    u16*  xpp   = woutp + (size_t)256 * 2048;   // padded to 128 rows (zeros)
    u16*  xnp   = (u16*)xnf;
    u16*  xcp   = (u16*)xcyf;

    for (int dir = 0; dir < 2; dir++) {
        int o = 1 + dir * 10;
        const float* nw   = (const float*)d_in[o + 0];
        const float* win  = (const float*)d_in[o + 1];
        const float* cw   = (const float*)d_in[o + 2];
        const float* cb   = (const float*)d_in[o + 3];
        const float* xp   = (const float*)d_in[o + 4];
        const float* dtw  = (const float*)d_in[o + 5];
        const float* dtbv = (const float*)d_in[o + 6];
        const float* Alog = (const float*)d_in[o + 7];
        const float* Dp   = (const float*)d_in[o + 8];
        const float* wout = (const float*)d_in[o + 9];

        wsplit_k<<<2048 * 256 / 256, 256, 0, stream>>>(win, winp, D_MODEL);
        wsplit_k<<<256 * 1024 / 256, 256, 0, stream>>>(wout, woutp, D_INNER);
        wsplit_pad_k<<<128 * 1024 / 256, 256, 0, stream>>>(xp, xpp, D_INNER, 48);

        for (int b0 = 0; b0 < 8; b0 += nb) {
            const float* xin = input + (size_t)b0 * SEQ * D_MODEL;
            float* cout = out + (size_t)b0 * SEQ * 2 * D_MODEL;

            rmsnorm_k<<<R, 256, 0, stream>>>(xin, nw, xnp);
            // in_proj: xz[R,2048] = xn * win^T, KL=256 -> 8 fused windows
            gemm_mfma<<<dim3(R / 128, 16, 1), 256, 0, stream>>>(
                xnp, 512, winp, 512, xz, 2 * D_INNER, D_MODEL, D_MODEL, 0,
                2 * D_INNER);
            conv_silu_k<<<R, 256, 0, stream>>>(xz, cw, cb, xcp, dir);
            // x_proj: partials[8][R,48] -> H region, KL=1024, split-K=8
            gemm_mfma<<<dim3(R / 128, 1, 8), 256, 0, stream>>>(
                xcp, 2048, xpp, 2048, H, 48, D_INNER, D_INNER / 8,
                (size_t)R * 48, 48);
            reduce_dbl_k<<<R * 48 / 256, 256, 0, stream>>>(H, dbl, (size_t)R * 48);
            if (usedt) {
                scan_p1<true><<<NC * nb * 4, 256, 0, stream>>>(
                    xcp, dbl, dtw, dtbv, Alog, Sarr, H, dtbf, nb, TC, dir);
                scan_p2<<<NCH / 256, 256, 0, stream>>>(Sarr, H, Alog, nb, NC);
                scan_p3<true><<<NC * nb * 4, 256, 0, stream>>>(
                    xcp, dbl, dtw, dtbv, xz, Alog, Dp, H, dtbf, nb, TC, dir);
            } else {
                scan_p1<false><<<NC * nb * 4, 256, 0, stream>>>(
                    xcp, dbl, dtw, dtbv, Alog, Sarr, H, nullptr, nb, TC, dir);
                scan_p2<<<NCH / 256, 256, 0, stream>>>(Sarr, H, Alog, nb, NC);
                scan_p3<false><<<NC * nb * 4, 256, 0, stream>>>(
                    xcp, dbl, dtw, dtbv, xz, Alog, Dp, H, nullptr, nb, TC, dir);
            }
            // out_proj: y_pair * wout^T, partials -> xcyf (xcp dead), z=2
            gemm_mfma<<<dim3(R / 128, 2, 2), 256, 0, stream>>>(
                (const u16*)xz, 4096, woutp, 2048, xcyf, 256, D_INNER,
                D_INNER / 2, (size_t)R * 256, 256);
            reduce_out_k<<<R * 64 / 256, 256, 0, stream>>>(
                xcyf, xin, cout, R, dir * D_MODEL, 2);
        }
    }
}

// Round 11
// 706.394 us; speedup vs baseline: 1.4717x; 1.1115x over previous
//
#include <hip/hip_runtime.h>

typedef unsigned short u16;
typedef __bf16 bf16x8 __attribute__((ext_vector_type(8)));
typedef float f32x4 __attribute__((ext_vector_type(4)));
typedef float f32x2 __attribute__((ext_vector_type(2)));

#define D_MODEL 256
#define D_INNER 1024
#define NST     16
#define SEQ     2048
#define LOG2E   1.4426950408889634f
#define PKFMA(a, b, c) __builtin_elementwise_fma(a, b, c)

static __device__ __forceinline__ float bf2f(u16 u) {
    union { float f; unsigned v; } x; x.v = ((unsigned)u) << 16; return x.f;
}
static __device__ __forceinline__ u16 f2bf(float f) {
    union { float f; unsigned u; } x; x.f = f;
    unsigned r = 0x7FFF + ((x.u >> 16) & 1);
    return (u16)((x.u + r) >> 16);
}

// async global->LDS, 16B per lane, LDS dest = wave-uniform base + lane*16
#define GLOAD_LDS16(g, l)                                            \
    __builtin_amdgcn_global_load_lds(                                \
        (const __attribute__((address_space(1))) void*)(g),          \
        (__attribute__((address_space(3))) void*)(l), 16, 0, 0)

// ---- RMSNorm -> split-bf16 pair output: row = [256 hi | 256 lo] u16 ----
__global__ __launch_bounds__(256) void rmsnorm_k(const float* __restrict__ x,
                                                 const float* __restrict__ w,
                                                 u16* __restrict__ xnp) {
    int row = blockIdx.x, t = threadIdx.x;
    float v = x[(size_t)row * D_MODEL + t];
    float s = v * v;
    #pragma unroll
    for (int o = 32; o; o >>= 1) s += __shfl_xor(s, o, 64);
    __shared__ float red[4];
    if ((t & 63) == 0) red[t >> 6] = s;
    __syncthreads();
    float tot = red[0] + red[1] + red[2] + red[3];
    float scale = rsqrtf(tot * (1.0f / D_MODEL) + 1e-5f);
    float xv = v * scale * w[t];
    u16 hi = f2bf(xv);
    u16 lo = f2bf(xv - bf2f(hi));
    xnp[(size_t)row * 512 + t] = hi;
    xnp[(size_t)row * 512 + 256 + t] = lo;
}

// ---- weight split: src[N*K] f32 -> dst[N][2K] bf16 (hi | lo) -----------
__global__ __launch_bounds__(256) void wsplit_k(const float* __restrict__ src,
                                                u16* __restrict__ dst, int K) {
    int i = blockIdx.x * 256 + threadIdx.x;
    int n = i / K, k = i - n * K;
    float v = src[i];
    u16 hi = f2bf(v);
    u16 lo = f2bf(v - bf2f(hi));
    dst[(size_t)n * 2 * K + k] = hi;
    dst[(size_t)n * 2 * K + K + k] = lo;
}

// ---- weight split with zero-padded rows (for x_proj: 48 real -> 128) ----
__global__ __launch_bounds__(256) void wsplit_pad_k(const float* __restrict__ src,
                                                    u16* __restrict__ dst, int K,
                                                    int Nreal) {
    int i = blockIdx.x * 256 + threadIdx.x;
    int n = i / K, k = i - n * K;
    float v = 0.0f;
    if (n < Nreal) v = src[i];
    u16 hi = f2bf(v);
    u16 lo = f2bf(v - bf2f(hi));
    dst[(size_t)n * 2 * K + k] = hi;
    dst[(size_t)n * 2 * K + K + k] = lo;
}

// ---- FUSED split-bf16 MFMA GEMM, 128x128 tile ---------------------------
// Per 32-real-k window, stage {Ah,Al,Wh,Wl} once and compute all 3 split
// terms (AhWh + AhWl + AlWh) into the same acc: 16 b128 reads per 48 MFMA.
// kslice = REAL k per z-slice (multiple of 32).
__global__ __launch_bounds__(256) void gemm_mfma(const u16* __restrict__ Ap, int lda,
                                                 const u16* __restrict__ Wp, int ldw,
                                                 float* __restrict__ C, int ldc,
                                                 int KL, int kslice, size_t zstride,
                                                 int Nreal) {
    __shared__ u16 As[128][64];
    __shared__ u16 Ws[128][64];
    const int m0 = blockIdx.x * 128, n0 = blockIdx.y * 128;
    const int tid = threadIdx.x;
    const int wave = tid >> 6, lane = tid & 63;
    const int wm = (wave >> 1) * 64, wn = (wave & 1) * 64;
    const int lm = lane & 15, quad = lane >> 4;

    const int srow = lane >> 3;                 // == row & 7
    const int schunk = (lane & 7) ^ srow;       // swizzled logical chunk
    const int scol = (schunk < 4) ? schunk * 8 : KL + (schunk - 4) * 8;
    const int rloc = wave * 8 + srow;

    f32x4 acc[4][4] = {};

    const int kb0 = blockIdx.z * kslice;
    for (int ko = kb0; ko < kb0 + kslice; ko += 32) {
        #pragma unroll
        for (int p = 0; p < 4; p++) {
            int row = p * 32 + rloc;
            GLOAD_LDS16(Ap + (size_t)(m0 + row) * lda + ko + scol,
                        &As[p * 32 + wave * 8][0]);
            GLOAD_LDS16(Wp + (size_t)(n0 + row) * ldw + ko + scol,
                        &Ws[p * 32 + wave * 8][0]);
        }
        __syncthreads();
        const int ph = ((quad ^ lm) & 7) * 8;   // phys offset of logical 'quad'
        bf16x8 bh[4], bl[4];
        #pragma unroll
        for (int j = 0; j < 4; j++) {
            const u16* wr = &Ws[wn + j * 16 + lm][0];
            bh[j] = *(const bf16x8*)(wr + ph);
            bl[j] = *(const bf16x8*)(wr + (ph ^ 32));
        }
        #pragma unroll
        for (int i = 0; i < 4; i++) {
            const u16* ar = &As[wm + i * 16 + lm][0];
            bf16x8 ah = *(const bf16x8*)(ar + ph);
            bf16x8 al = *(const bf16x8*)(ar + (ph ^ 32));
            #pragma unroll
            for (int j = 0; j < 4; j++) {
                acc[i][j] = __builtin_amdgcn_mfma_f32_16x16x32_bf16(
                    ah, bh[j], acc[i][j], 0, 0, 0);
                acc[i][j] = __builtin_amdgcn_mfma_f32_16x16x32_bf16(
                    ah, bl[j], acc[i][j], 0, 0, 0);
                acc[i][j] = __builtin_amdgcn_mfma_f32_16x16x32_bf16(
                    al, bh[j], acc[i][j], 0, 0, 0);
            }
        }
        __syncthreads();
    }

    float* Cz = C + zstride * blockIdx.z;
    #pragma unroll
    for (int i = 0; i < 4; i++)
        #pragma unroll
        for (int j = 0; j < 4; j++)
            #pragma unroll
            for (int r = 0; r < 4; r++) {
                int mrow = m0 + wm + i * 16 + quad * 4 + r;   // C/D: row=quad*4+reg
                int ncol = n0 + wn + j * 16 + lm;             //      col=lane&15
                if (ncol < Nreal)
                    Cz[(size_t)mrow * ldc + ncol] = acc[i][j][r];
            }
}

// ------ reduce 8 x_proj partials -> dbl[R*48] -----------------------------
__global__ __launch_bounds__(256) void reduce_dbl_k(const float* __restrict__ pbuf,
                                                    float* __restrict__ dbl,
                                                    size_t RS) {
    size_t e = (size_t)blockIdx.x * 256 + threadIdx.x;
    float v = 0.0f;
    #pragma unroll
    for (int z = 0; z < 8; z++) v += pbuf[z * RS + e];
    dbl[e] = v;
}

// ------ reduce ns out_proj partials + residual -> out[m, coff + n] --------
__global__ __launch_bounds__(256) void reduce_out_k(const float* __restrict__ pbuf,
                                                    const float* __restrict__ res,
                                                    float* __restrict__ out,
                                                    int M, int coff, int ns) {
    int idx = blockIdx.x * 256 + threadIdx.x;
    int m = idx >> 6, n4 = (idx & 63) * 4;
    size_t e = (size_t)m * 256 + n4;
    size_t stride = (size_t)M * 256;
    float4 v = *(const float4*)(res + e);
    for (int s = 0; s < ns; s++) {
        float4 p = *(const float4*)(pbuf + s * stride + e);
        v.x += p.x; v.y += p.y; v.z += p.z; v.w += p.w;
    }
    *(float4*)(out + (size_t)m * 512 + coff + n4) = v;
}

// ---- depthwise causal conv + SiLU; out = split-bf16 pair ----------------
__global__ __launch_bounds__(256) void conv_silu_k(const float* __restrict__ xz,
                                                   const float* __restrict__ cw,
                                                   const float* __restrict__ cb,
                                                   u16* __restrict__ xcp, int dir) {
    int bx = blockIdx.x;
    int dgrp = bx & 3;
    int rowgrp = bx >> 2;
    int l0 = (rowgrp & (SEQ / 4 - 1)) * 4;
    int b = rowgrp >> 9;
    int d = dgrp * 256 + threadIdx.x;

    int base = dir ? l0 : (l0 - 3);
    float x[7];
    #pragma unroll
    for (int i = 0; i < 7; i++) {
        int lr = base + i;
        x[i] = (lr >= 0 && lr < SEQ)
             ? xz[((size_t)b * SEQ + lr) * (2 * D_INNER) + d] : 0.0f;
    }
    float w0 = cw[d * 4 + 0], w1 = cw[d * 4 + 1];
    float w2 = cw[d * 4 + 2], w3 = cw[d * 4 + 3];
    float bias = cb[d];

    #pragma unroll
    for (int li = 0; li < 4; li++) {
        float acc;
        if (dir == 0)
            acc = bias + w0 * x[li] + w1 * x[li + 1] + w2 * x[li + 2] + w3 * x[li + 3];
        else
            acc = bias + w3 * x[li] + w2 * x[li + 1] + w1 * x[li + 2] + w0 * x[li + 3];
        float s = acc / (1.0f + __expf(-acc));
        u16 hi = f2bf(s);
        u16 lo = f2bf(s - bf2f(hi));
        size_t row = (size_t)b * SEQ + l0 + li;
        xcp[row * 2048 + d] = hi;
        xcp[row * 2048 + D_INNER + d] = lo;
    }
}

// ---- scan phase 1: per-chunk H (h_in=0) and S=sum(dt); dbl in LDS -------
// Packed-f32 (v_pk_*) inner loop: state as f32x2[8] halves VALU issue count
// of the dot / dA-powers / h-update.  Fast path keeps only A2_0 in regs;
// the (never-taken-in-practice) general path recomputes A2[n] per step so
// it stays register-light and doesn't set the kernel's VGPR allocation.
// No min-waves bound (R7: forcing 8/EU clamped VGPR->32 and spilled).
__global__ __launch_bounds__(256) void scan_p1(const u16* __restrict__ xcp,
                                               const float* __restrict__ dbl,
                                               const float* __restrict__ dtw,
                                               const float* __restrict__ dtb,
                                               const float* __restrict__ Alog,
                                               float* __restrict__ Sarr,
                                               float* __restrict__ H,
                                               int nb, int TC, int dir) {
    __shared__ float sdbl[32 * 48];            // TC <= 32
    int t = threadIdx.x;
    int nblk4 = nb * 4;
    int c = blockIdx.x / nblk4;
    int rem = blockIdx.x - c * nblk4;
    int b = rem >> 2, dblk = rem & 3;
    int d = dblk * 256 + t;

    int lbase = dir ? (SEQ - (c + 1) * TC) : (c * TC);
    {
        const float* src = dbl + ((size_t)b * SEQ + lbase) * 48;
        int nf4 = TC * 12;
        for (int i = t; i < nf4; i += 256)
            *(f32x4*)&sdbl[i * 4] = *(const f32x4*)(src + i * 4);
    }

    const float* ap = Alog + (size_t)d * NST;
    const float* wp = dtw + (size_t)d * NST;
    f32x2 wdt2[8];
    #pragma unroll
    for (int j = 0; j < 8; j++) wdt2[j] = (f32x2){wp[2 * j], wp[2 * j + 1]};
    float bdt = dtb[d];
    float A2_0 = -__expf(ap[0]) * LOG2E;
    bool fast = true;
    #pragma unroll
    for (int n = 0; n < 16; n++) {
        float A2n = -__expf(ap[n]) * LOG2E;
        fast = fast && (fabsf(A2n - (n + 1) * A2_0) < 1e-3f);
    }

    f32x2 h2[8] = {};
    float S = 0.0f;

    int lstep = dir ? -1 : 1;
    int l0 = dir ? (lbase + TC - 1) : lbase;
    const u16* up = xcp + ((size_t)b * SEQ + l0) * 2048 + d;
    ptrdiff_t ups = (ptrdiff_t)lstep * 2048;
    const float* dr = sdbl + (dir ? (TC - 1) * 48 : 0);
    ptrdiff_t drs = (ptrdiff_t)lstep * 48;

    __syncthreads();

    if (fast) {
        u16 uh = up[0], ul = up[D_INNER];
        #pragma unroll 2
        for (int s = 0; s < TC; s++) {
            u16 nh = up[ups], nl = up[ups + D_INNER];   // prefetch next step
            f32x2 dl2[8], B2[8];
            #pragma unroll
            for (int q = 0; q < 4; q++) {
                f32x4 dq = *(const f32x4*)(dr + q * 4);
                f32x4 bq = *(const f32x4*)(dr + 16 + q * 4);
                dl2[2 * q]     = __builtin_shufflevector(dq, dq, 0, 1);
                dl2[2 * q + 1] = __builtin_shufflevector(dq, dq, 2, 3);
                B2[2 * q]      = __builtin_shufflevector(bq, bq, 0, 1);
                B2[2 * q + 1]  = __builtin_shufflevector(bq, bq, 2, 3);
            }
            float u = bf2f(uh) + bf2f(ul);
            f32x2 acc2 = (f32x2){bdt, 0.0f};
            #pragma unroll
            for (int j = 0; j < 8; j++) acc2 = PKFMA(dl2[j], wdt2[j], acc2);
            float acc = acc2.x + acc2.y;
            float dt = (acc > 20.0f) ? acc : __logf(1.0f + __expf(acc));
            S += dt;
            f32x2 dtu2 = (f32x2){dt * u, dt * u};
            float e1 = exp2f(A2_0 * dt);
            float e2 = e1 * e1;
            f32x2 e22 = (f32x2){e2, e2};
            f32x2 dA2[8];
            dA2[0] = (f32x2){e1, e2};
            #pragma unroll
            for (int j = 1; j < 8; j++) dA2[j] = dA2[j - 1] * e22;
            #pragma unroll
            for (int j = 0; j < 8; j++)
                h2[j] = PKFMA(h2[j], dA2[j], dtu2 * B2[j]);
            uh = nh; ul = nl;
            dr += drs; up += ups;
        }
    } else {
        u16 uh = up[0], ul = up[D_INNER];
        for (int s = 0; s < TC; s++) {
            u16 nh = up[ups], nl = up[ups + D_INNER];
            float u = bf2f(uh) + bf2f(ul);
            float acc = bdt;
            #pragma unroll
            for (int j = 0; j < 8; j++) {
                acc += dr[2 * j] * wdt2[j].x;
                acc += dr[2 * j + 1] * wdt2[j].y;
            }
            float dt = (acc > 20.0f) ? acc : __logf(1.0f + __expf(acc));
            S += dt;
            float dtu = dt * u;
            #pragma unroll
            for (int j = 0; j < 8; j++) {
                float a0 = -__expf(ap[2 * j]) * LOG2E;
                float a1 = -__expf(ap[2 * j + 1]) * LOG2E;
                h2[j].x = h2[j].x * exp2f(a0 * dt) + dtu * dr[16 + 2 * j];
                h2[j].y = h2[j].y * exp2f(a1 * dt) + dtu * dr[16 + 2 * j + 1];
            }
            uh = nh; ul = nl;
            dr += drs; up += ups;
        }
    }

    size_t NCH = (size_t)nb * 16384;
    size_t base = (size_t)c * NCH + ((size_t)b * 1024 + d) * 16;
    #pragma unroll
    for (int q = 0; q < 4; q++) {
        f32x4 hv = __builtin_shufflevector(h2[2 * q], h2[2 * q + 1], 0, 1, 2, 3);
        *(f32x4*)&H[base + q * 4] = hv;
    }
    Sarr[(size_t)c * nb * 1024 + (size_t)b * 1024 + d] = S;
}

// ------- scan phase 2: combine chunk states; H repurposed as h_in --------
// P reconstructed from scalar S: Pc = exp2(A2[n] * S[c][b][d]).
__global__ __launch_bounds__(256) void scan_p2(const float* __restrict__ Sarr,
                                               float* __restrict__ H,
                                               const float* __restrict__ Alog,
                                               int nb, int NC) {
    size_t ch = (size_t)blockIdx.x * 256 + threadIdx.x;
    int n = (int)(ch & 15);
    int d = (int)((ch >> 4) & 1023);
    int bb = (int)(ch >> 14);
    float A2n = -__expf(Alog[(size_t)d * NST + n]) * LOG2E;
    size_t NCH = (size_t)nb * 16384;
    size_t snch = (size_t)nb * 1024;
    size_t sbase = (size_t)bb * 1024 + d;
    float h = 0.0f;
    for (int c = 0; c < NC; c++) {
        float Pc = exp2f(A2n * Sarr[c * snch + sbase]);
        size_t i = (size_t)c * NCH + ch;
        float Hc = H[i];
        H[i] = h;
        h = Hc + Pc * h;
    }
}

// ---- scan phase 3: recurrence + silu(z) + y pair; packed-f32 body -------
__global__ __launch_bounds__(256) void scan_p3(const u16* __restrict__ xcp,
                                               const float* __restrict__ dbl,
                                               const float* __restrict__ dtw,
                                               const float* __restrict__ dtb,
                                               float* __restrict__ xz,
                                               const float* __restrict__ Alog,
                                               const float* __restrict__ Dp,
                                               const float* __restrict__ hin,
                                               int nb, int TC, int dir) {
    __shared__ float sdbl[32 * 48];
    int t = threadIdx.x;
    int nblk4 = nb * 4;
    int c = blockIdx.x / nblk4;
    int rem = blockIdx.x - c * nblk4;
    int b = rem >> 2, dblk = rem & 3;
    int d = dblk * 256 + t;

    int lbase = dir ? (SEQ - (c + 1) * TC) : (c * TC);
    {
        const float* src = dbl + ((size_t)b * SEQ + lbase) * 48;
        int nf4 = TC * 12;
        for (int i = t; i < nf4; i += 256)
            *(f32x4*)&sdbl[i * 4] = *(const f32x4*)(src + i * 4);
    }

    const float* ap = Alog + (size_t)d * NST;
    const float* wp = dtw + (size_t)d * NST;
    f32x2 wdt2[8];
    #pragma unroll
    for (int j = 0; j < 8; j++) wdt2[j] = (f32x2){wp[2 * j], wp[2 * j + 1]};
    float bdt = dtb[d];
    float Dd = Dp[d];
    float A2_0 = -__expf(ap[0]) * LOG2E;
    bool fast = true;
    #pragma unroll
    for (int n = 0; n < 16; n++) {
        float A2n = -__expf(ap[n]) * LOG2E;
        fast = fast && (fabsf(A2n - (n + 1) * A2_0) < 1e-3f);
    }

    size_t NCH = (size_t)nb * 16384;
    size_t base = (size_t)c * NCH + ((size_t)b * 1024 + d) * 16;
    f32x2 h2[8];
    #pragma unroll
    for (int q = 0; q < 4; q++) {
        f32x4 hv = *(const f32x4*)&hin[base + q * 4];
        h2[2 * q]     = __builtin_shufflevector(hv, hv, 0, 1);
        h2[2 * q + 1] = __builtin_shufflevector(hv, hv, 2, 3);
    }

    int lstep = dir ? -1 : 1;
    int l0 = dir ? (lbase + TC - 1) : lbase;
    size_t row0 = (size_t)b * SEQ + l0;
    const u16* up = xcp + row0 * 2048 + d;
    const float* zp = xz + row0 * 2048 + D_INNER + d;
    u16* yp = (u16*)(xz + row0 * 2048) + d;
    ptrdiff_t ups = (ptrdiff_t)lstep * 2048;
    ptrdiff_t zps = (ptrdiff_t)lstep * 2048;
    ptrdiff_t yps = (ptrdiff_t)lstep * 4096;   // u16 pitch of a 2048-float row
    const float* dr = sdbl + (dir ? (TC - 1) * 48 : 0);
    ptrdiff_t drs = (ptrdiff_t)lstep * 48;

    __syncthreads();

    if (fast) {
        u16 uh = up[0], ul = up[D_INNER];
        float zc = *zp;
        #pragma unroll 2
        for (int s = 0; s < TC; s++) {
            u16 nh = up[ups], nl = up[ups + D_INNER];   // prefetch next step
            float zn = zp[zps];
            f32x2 dl2[8], B2[8], C2[8];
            #pragma unroll
            for (int q = 0; q < 4; q++) {
                f32x4 dq = *(const f32x4*)(dr + q * 4);
                f32x4 bq = *(const f32x4*)(dr + 16 + q * 4);
                f32x4 cq = *(const f32x4*)(dr + 32 + q * 4);
                dl2[2 * q]     = __builtin_shufflevector(dq, dq, 0, 1);
                dl2[2 * q + 1] = __builtin_shufflevector(dq, dq, 2, 3);
                B2[2 * q]      = __builtin_shufflevector(bq, bq, 0, 1);
                B2[2 * q + 1]  = __builtin_shufflevector(bq, bq, 2, 3);
                C2[2 * q]      = __builtin_shufflevector(cq, cq, 0, 1);
                C2[2 * q + 1]  = __builtin_shufflevector(cq, cq, 2, 3);
            }
            float u = bf2f(uh) + bf2f(ul);
            f32x2 acc2 = (f32x2){bdt, 0.0f};
            #pragma unroll
            for (int j = 0; j < 8; j++) acc2 = PKFMA(dl2[j], wdt2[j], acc2);
            float acc = acc2.x + acc2.y;
            float dt = (acc > 20.0f) ? acc : __logf(1.0f + __expf(acc));
            f32x2 dtu2 = (f32x2){dt * u, dt * u};
            float e1 = exp2f(A2_0 * dt);
            float e2 = e1 * e1;
            f32x2 e22 = (f32x2){e2, e2};
            f32x2 dA2[8];
            dA2[0] = (f32x2){e1, e2};
            #pragma unroll
            for (int j = 1; j < 8; j++) dA2[j] = dA2[j - 1] * e22;
            #pragma unroll
            for (int j = 0; j < 8; j++)
                h2[j] = PKFMA(h2[j], dA2[j], dtu2 * B2[j]);

            f32x2 y2a = h2[0] * C2[0];
            f32x2 y2b = h2[1] * C2[1];
            #pragma unroll
            for (int j = 2; j < 8; j += 2) {
                y2a = PKFMA(h2[j], C2[j], y2a);
                y2b = PKFMA(h2[j + 1], C2[j + 1], y2b);
            }
            f32x2 y2 = y2a + y2b;

            float g = zc / (1.0f + __expf(-zc));
            float y = (y2.x + y2.y + u * Dd) * g;

            u16 hi = f2bf(y);
            yp[0] = hi;
            yp[D_INNER] = f2bf(y - bf2f(hi));

            uh = nh; ul = nl; zc = zn;
            dr += drs; up += ups; zp += zps; yp += yps;
        }
    } else {
        u16 uh = up[0], ul = up[D_INNER];
        float zc = *zp;
        for (int s = 0; s < TC; s++) {
            u16 nh = up[ups], nl = up[ups + D_INNER];
            float zn = zp[zps];
            float u = bf2f(uh) + bf2f(ul);
            float acc = bdt;
            #pragma unroll
            for (int j = 0; j < 8; j++) {
                acc += dr[2 * j] * wdt2[j].x;
                acc += dr[2 * j + 1] * wdt2[j].y;
            }
            float dt = (acc > 20.0f) ? acc : __logf(1.0f + __expf(acc));
            float dtu = dt * u;
            float psum = 0.0f;
            #pragma unroll
            for (int j = 0; j < 8; j++) {
                float a0 = -__expf(ap[2 * j]) * LOG2E;
                float a1 = -__expf(ap[2 * j + 1]) * LOG2E;
                h2[j].x = h2[j].x * exp2f(a0 * dt) + dtu * dr[16 + 2 * j];
                h2[j].y = h2[j].y * exp2f(a1 * dt) + dtu * dr[16 + 2 * j + 1];
                psum += h2[j].x * dr[32 + 2 * j] + h2[j].y * dr[32 + 2 * j + 1];
            }
            float g = zc / (1.0f + __expf(-zc));
            float y = (psum + u * Dd) * g;
            u16 hi = f2bf(y);
            yp[0] = hi;
            yp[D_INNER] = f2bf(y - bf2f(hi));
            uh = nh; ul = nl; zc = zn;
            dr += drs; up += ups; zp += zps; yp += yps;
        }
    }
}

// ---------------- host launch --------------------------------------------
extern "C" void kernel_launch(void* const* d_in, const int* in_sizes, int n_in,
                              void* d_out, int out_size, void* d_ws, size_t ws_size,
                              hipStream_t stream) {
    const float* input = (const float*)d_in[0];
    float* out = (float*)d_out;

    const size_t wspl = (size_t)(2048 * 512 + 256 * 2048 + 128 * 2048) * 2;
    const int TC = 32;
    const int NC = SEQ / TC;
    // Workspace: H + S + per-batch buffers.  x_proj partials alias H;
    // out_proj partials (z=2) alias xcyf (xcp dead after p3).
    auto fitsz = [&](int nb_) {
        size_t fl = (size_t)NC * nb_ * (16384 + 1024)
                  + (size_t)nb_ * SEQ * (256 + 2048 + 1024 + 48);
        return fl * 4 + wspl <= ws_size;
    };
    int nb = 8;
    while (nb > 1 && !fitsz(nb)) nb >>= 1;
    const int R = nb * SEQ;
    const int NCH = nb * 16384;
    const size_t Hsz = (size_t)NC * NCH;

    float* H    = (float*)d_ws;        // chunk h / h_in; x_proj partials alias
    float* Sarr = H + Hsz;
    float* xnf  = Sarr + (size_t)NC * nb * 1024;
    float* xz   = xnf + (size_t)R * D_MODEL;
    float* xcyf = xz  + (size_t)R * 2 * D_INNER;   // xcp pair / out_proj partials
    float* dbl  = xcyf + (size_t)R * D_INNER;
    u16*  winp  = (u16*)(dbl + (size_t)R * 48);
    u16*  woutp = winp + (size_t)2048 * 512;
    u16*  xpp   = woutp + (size_t)256 * 2048;   // padded to 128 rows (zeros)
    u16*  xnp   = (u16*)xnf;
    u16*  xcp   = (u16*)xcyf;

    for (int dir = 0; dir < 2; dir++) {
        int o = 1 + dir * 10;
        const float* nw   = (const float*)d_in[o + 0];
        const float* win  = (const float*)d_in[o + 1];
        const float* cw   = (const float*)d_in[o + 2];
        const float* cb   = (const float*)d_in[o + 3];
        const float* xp   = (const float*)d_in[o + 4];
        const float* dtw  = (const float*)d_in[o + 5];
        const float* dtbv = (const float*)d_in[o + 6];
        const float* Alog = (const float*)d_in[o + 7];
        const float* Dp   = (const float*)d_in[o + 8];
        const float* wout = (const float*)d_in[o + 9];

        wsplit_k<<<2048 * 256 / 256, 256, 0, stream>>>(win, winp, D_MODEL);
        wsplit_k<<<256 * 1024 / 256, 256, 0, stream>>>(wout, woutp, D_INNER);
        wsplit_pad_k<<<128 * 1024 / 256, 256, 0, stream>>>(xp, xpp, D_INNER, 48);

        for (int b0 = 0; b0 < 8; b0 += nb) {
            const float* xin = input + (size_t)b0 * SEQ * D_MODEL;
            float* cout = out + (size_t)b0 * SEQ * 2 * D_MODEL;

            rmsnorm_k<<<R, 256, 0, stream>>>(xin, nw, xnp);
            // in_proj: xz[R,2048] = xn * win^T, KL=256 -> 8 fused windows
            gemm_mfma<<<dim3(R / 128, 16, 1), 256, 0, stream>>>(
                xnp, 512, winp, 512, xz, 2 * D_INNER, D_MODEL, D_MODEL, 0,
                2 * D_INNER);
            conv_silu_k<<<R, 256, 0, stream>>>(xz, cw, cb, xcp, dir);
            // x_proj: partials[8][R,48] -> H region, KL=1024, split-K=8
            gemm_mfma<<<dim3(R / 128, 1, 8), 256, 0, stream>>>(
                xcp, 2048, xpp, 2048, H, 48, D_INNER, D_INNER / 8,
                (size_t)R * 48, 48);
            reduce_dbl_k<<<R * 48 / 256, 256, 0, stream>>>(H, dbl, (size_t)R * 48);
            scan_p1<<<NC * nb * 4, 256, 0, stream>>>(
                xcp, dbl, dtw, dtbv, Alog, Sarr, H, nb, TC, dir);
            scan_p2<<<NCH / 256, 256, 0, stream>>>(Sarr, H, Alog, nb, NC);
            scan_p3<<<NC * nb * 4, 256, 0, stream>>>(
                xcp, dbl, dtw, dtbv, xz, Alog, Dp, H, nb, TC, dir);
            // out_proj: y_pair * wout^T, partials -> xcyf (xcp dead), z=2
            gemm_mfma<<<dim3(R / 128, 2, 2), 256, 0, stream>>>(
                (const u16*)xz, 4096, woutp, 2048, xcyf, 256, D_INNER,
                D_INNER / 2, (size_t)R * 256, 256);
            reduce_out_k<<<R * 64 / 256, 256, 0, stream>>>(
                xcyf, xin, cout, R, dir * D_MODEL, 2);
        }
    }
}